// Round 5
// baseline (984.514 us; speedup 1.0000x reference)
//
#include <hip/hip_runtime.h>
#include <stdio.h>

// ---------------------------------------------------------------------------
// WindowAttention: partition -> QKV gemm -> tiny attention over B axis ->
// fused (out_proj @ mlp) gemm -> reverse.
// GEMM: 256x256 bf16 MFMA, cross-tile software-pipelined reads:
//   MFMA1 uses aLo read at END of previous tile (dead-slot reuse, no extra
//   VGPR generation); partial lgkmcnt(8) lets aHi drain under MFMA1; the
//   vmcnt(8)+barrier moves before MFMA2 so next-tile aLo drains under MFMA2.
// ---------------------------------------------------------------------------

typedef __attribute__((ext_vector_type(4))) float f32x4;
typedef __attribute__((ext_vector_type(8))) short s16x8;
typedef __attribute__((ext_vector_type(2))) unsigned short u16x2;
typedef __attribute__((ext_vector_type(4))) unsigned short u16x4;

#define NB 4        // batch B (attention seq len)
#define NC 32       // channels
#define NTOK 4096   // N = 16^3 windows
#define ED 2048     // embed dim E
#define NH 16       // heads
#define HD 128      // head dim

__device__ __forceinline__ unsigned short f2bf(float f) {
    union { float f; unsigned int u; } v; v.f = f;
    unsigned int r = (v.u + 0x7fffu + ((v.u >> 16) & 1u)) >> 16;
    return (unsigned short)r;
}
__device__ __forceinline__ float bf2f(unsigned short u) {
    union { unsigned int u; float f; } v; v.u = ((unsigned int)u) << 16;
    return v.f;
}

#define BARRIER() asm volatile("s_barrier" ::: "memory")
#define LGKM0() do { asm volatile("s_waitcnt lgkmcnt(0)" ::: "memory"); \
                     __builtin_amdgcn_sched_barrier(0); } while (0)
#define LGKM8() do { asm volatile("s_waitcnt lgkmcnt(8)" ::: "memory"); \
                     __builtin_amdgcn_sched_barrier(0); } while (0)
#define VMCNT(n) asm volatile("s_waitcnt vmcnt(" #n ")" ::: "memory")

// ---------------- fp32 -> bf16 convert (weights) ----------------
__global__ void f32_to_bf16_kernel(const float* __restrict__ src,
                                   unsigned short* __restrict__ dst, int n4) {
    int i = blockIdx.x * blockDim.x + threadIdx.x;
    if (i >= n4) return;
    f32x4 v = *(const f32x4*)(src + (size_t)i * 4);
    u16x4 w;
    w.x = f2bf(v.x); w.y = f2bf(v.y); w.z = f2bf(v.z); w.w = f2bf(v.w);
    *(u16x4*)(dst + (size_t)i * 4) = w;
}

// ---------------- transpose f32 -> bf16: dst[j,k] = src[k,j] ----------------
__global__ __launch_bounds__(256) void transpose_bf16_kernel(
    const float* __restrict__ src, unsigned short* __restrict__ dst, int n) {
    __shared__ float lds[64][68];
    const int bx = blockIdx.x * 64;   // j base
    const int by = blockIdx.y * 64;   // k base
    const int t  = threadIdx.x;
    const int r  = t >> 2;            // 0..63
    const int c4 = (t & 3) * 16;      // 0/16/32/48
    const float* s = src + (size_t)(by + r) * n + bx + c4;
    #pragma unroll
    for (int i = 0; i < 4; ++i)
        *(f32x4*)&lds[r][c4 + i * 4] = *(const f32x4*)(s + i * 4);
    __syncthreads();
    unsigned short* d = dst + (size_t)(bx + r) * n + by + c4;
    #pragma unroll
    for (int i = 0; i < 4; ++i) {
        u16x4 w;
        w.x = f2bf(lds[c4 + i * 4 + 0][r]);
        w.y = f2bf(lds[c4 + i * 4 + 1][r]);
        w.z = f2bf(lds[c4 + i * 4 + 2][r]);
        w.w = f2bf(lds[c4 + i * 4 + 3][r]);
        *(u16x4*)(d + i * 4) = w;
    }
}

// ---------------- b_comb = mlp_w @ out_proj_b + mlp_b ----------------
__global__ void bcomb_kernel(const float* __restrict__ mlp_w,
                             const float* __restrict__ opb,
                             const float* __restrict__ mlpb,
                             float* __restrict__ bcomb) {
    int i = blockIdx.x * blockDim.x + threadIdx.x;   // 0..2047
    const float* row = mlp_w + (size_t)i * ED;
    float s = 0.0f;
    for (int k = 0; k < ED; k += 4) {
        f32x4 a = *(const f32x4*)(row + k);
        f32x4 b = *(const f32x4*)(opb + k);
        s += a.x * b.x + a.y * b.y + a.z * b.z + a.w * b.w;
    }
    bcomb[i] = s + mlpb[i];
}

// ---------------- window partition: x -> tok (B,N,E) bf16 ----------------
__global__ void partition_kernel(const float* __restrict__ x,
                                 unsigned short* __restrict__ tok) {
    int idx = blockIdx.x * blockDim.x + threadIdx.x;
    int m = idx & 15;
    int t = idx >> 4;
    int Y = t & 63; t >>= 6;
    int X = t & 63; t >>= 6;
    int c = t & 31;
    int b = t >> 5;
    f32x4 xv = *(const f32x4*)(x + (size_t)idx * 4);
    int nx = X >> 2, px = X & 3;
    int ny = Y >> 2, py = Y & 3;
    int n = nx * 256 + ny * 16 + m;
    int e = c * 64 + px * 16 + py * 4;
    size_t dst = (size_t)(b * NTOK + n) * ED + e;
    u16x4 w;
    w.x = f2bf(xv.x); w.y = f2bf(xv.y); w.z = f2bf(xv.z); w.w = f2bf(xv.w);
    *(u16x4*)&tok[dst] = w;
}

// ---------------- 128x128 4-wave bf16 GEMM (for small W_comb job) ----------
__global__ __launch_bounds__(256) void gemm128(
    const unsigned short* __restrict__ A,   // M x K bf16
    const unsigned short* __restrict__ W,   // Nout x K bf16
    const float* __restrict__ bias,         // Nout f32
    unsigned short* __restrict__ C,         // M x Nout bf16
    int M, int Nout, int K)
{
    __shared__ unsigned short ldsA[128 * 64];
    __shared__ unsigned short ldsW[128 * 64];

    const int tid  = threadIdx.x;
    const int wave = tid >> 6;
    const int lane = tid & 63;
    const int bm = blockIdx.x * 128;
    const int bn = blockIdx.y * 128;
    const int wm = (wave >> 1) * 64;
    const int wn = (wave & 1) * 64;

    f32x4 acc[4][4] = {};

    const int srow = lane >> 3;
    const int scol = (lane & 7) * 8;
    const int lrow = lane & 15;
    const int lk   = (lane >> 4) * 8;

    const int nkt = K >> 6;
    for (int kt = 0; kt < nkt; ++kt) {
        const int kbase = kt * 64;
        #pragma unroll
        for (int q = 0; q < 4; ++q) {
            int chunk = wave * 4 + q;
            int row = chunk * 8 + srow;
            const unsigned short* ga = A + (size_t)(bm + row) * K + kbase + scol;
            const unsigned short* gw = W + (size_t)(bn + row) * K + kbase + scol;
            __builtin_amdgcn_global_load_lds(
                (const __attribute__((address_space(1))) void*)ga,
                (__attribute__((address_space(3))) void*)(&ldsA[chunk * 512]),
                16, 0, 0);
            __builtin_amdgcn_global_load_lds(
                (const __attribute__((address_space(1))) void*)gw,
                (__attribute__((address_space(3))) void*)(&ldsW[chunk * 512]),
                16, 0, 0);
        }
        __syncthreads();

        #pragma unroll
        for (int ks = 0; ks < 2; ++ks) {
            const int k0 = ks * 32 + lk;
            s16x8 af[4], bf[4];
            #pragma unroll
            for (int m = 0; m < 4; ++m)
                af[m] = *(const s16x8*)&ldsA[(wm + m * 16 + lrow) * 64 + k0];
            #pragma unroll
            for (int n = 0; n < 4; ++n)
                bf[n] = *(const s16x8*)&ldsW[(wn + n * 16 + lrow) * 64 + k0];
            #pragma unroll
            for (int m = 0; m < 4; ++m)
                #pragma unroll
                for (int n = 0; n < 4; ++n)
                    acc[m][n] = __builtin_amdgcn_mfma_f32_16x16x32_bf16(
                        af[m], bf[n], acc[m][n], 0, 0, 0);
        }
        __syncthreads();
    }

    const int col   = lane & 15;
    const int rbase = (lane >> 4) * 4;
    #pragma unroll
    for (int n = 0; n < 4; ++n) {
        int cc = bn + wn + n * 16 + col;
        float bv = bias[cc];
        #pragma unroll
        for (int m = 0; m < 4; ++m)
            #pragma unroll
            for (int r = 0; r < 4; ++r) {
                int rr = bm + wm + m * 16 + rbase + r;
                C[(size_t)rr * Nout + cc] = f2bf(acc[m][n][r] + bv);
            }
    }
}

// ---------------- 256x256 pipelined bf16 GEMM ----------------
// C[r,j] = sum_k A[r,k] * W[j,k] + bias[j].  Requires M == 16384 and
// Nout % 1024 == 0.  8 waves (2M x 4N), per-wave 128x64, BK=64, LDS 128KB.
// Per K-tile t (buf db=t&1):
//   lgkm0 (aLo from prev iter) ; issue bl/bh(8) then aHi(8) ; lgkm8
//   MFMA1 (m0-3, aLo) || aHi drains ; lgkm0 ; barrier#1 (all reads done)
//   stage S(t+2) -> db ; vmcnt(8) ; barrier#2 (S(t+1) resident)
//   issue aLo'(t+1) from db^1 ; MFMA2 (m4-7, aHi) || aLo' drains
// Safety: stages into db touch regions whose reads all landed before
// barrier#1; aLo'(t+1) reads db^1, staged during t-1, resident per vmcnt(8)
// (in-flight = S(t+1) 8 + S(t+2) 8) + barrier#2. DS ops complete in order
// per wave, so lgkmcnt(8) after [8 B-reads][8 A-reads] covers the B-reads.
template <int OUT_BF16>
__global__ __launch_bounds__(512, 2) void gemm256(
    const unsigned short* __restrict__ A,   // M x K bf16
    const unsigned short* __restrict__ W,   // Nout x K bf16
    const float* __restrict__ bias,         // Nout f32
    void* __restrict__ Cv,                  // M x Nout (bf16 or f32)
    int M, int Nout, int K)
{
    __shared__ unsigned short ldsA[2][2][128 * 64];
    __shared__ unsigned short ldsB[2][2][128 * 64];

    const int tid  = threadIdx.x;
    const int wave = tid >> 6;
    const int lane = tid & 63;

    // L2-locality mapping (bijective, gm=64): XCD x owns m-band x; 8m x 4n
    // macro-tiles of 32 blocks = the concurrent set per XCD.
    const int f   = blockIdx.x;
    const int xcd = f & 7;
    const int r_  = f >> 3;
    const int mac = r_ >> 5;
    const int w_  = r_ & 31;
    const int bm  = (xcd * 8 + (w_ & 7)) * 256;
    const int bn  = (mac * 4 + (w_ >> 3)) * 256;

    const int wi    = wave >> 2;        // 0/1: M half
    const int wj    = wave & 3;         // 0-3: N quarter
    const int bhalf = wj >> 1;          // B half this wave reads
    const int bcol  = (wj & 1) * 64;    // col base within that half

    const int lrow = lane & 15;
    const int kq   = lane >> 4;                    // 0-3
    const int s0   = ((kq ^ (lrow & 7)) << 3);     // swizzled elem offset

    f32x4 acc[8][4] = {};

    const int nkt = K >> 6;

    const int srl   = lane >> 3;                         // 0-7
    const int sslot = (((lane & 7) ^ srl) << 3);         // pre-swizzled src off

    auto stA = [&](int db, int half, int tt) {
        const unsigned short* gb = A + (size_t)(bm + half * 128) * K + tt * 64;
        unsigned short* lb = &ldsA[db][half][0];
        #pragma unroll
        for (int q = 0; q < 2; ++q) {
            const int r0 = wave * 16 + q * 8;
            const unsigned short* ga = gb + (size_t)(r0 + srl) * K + sslot;
            __builtin_amdgcn_global_load_lds(
                (const __attribute__((address_space(1))) void*)ga,
                (__attribute__((address_space(3))) void*)(lb + r0 * 64),
                16, 0, 0);
        }
    };
    auto stB = [&](int db, int half, int tt) {
        const unsigned short* gb = W + (size_t)(bn + half * 128) * K + tt * 64;
        unsigned short* lb = &ldsB[db][half][0];
        #pragma unroll
        for (int q = 0; q < 2; ++q) {
            const int r0 = wave * 16 + q * 8;
            const unsigned short* ga = gb + (size_t)(r0 + srl) * K + sslot;
            __builtin_amdgcn_global_load_lds(
                (const __attribute__((address_space(1))) void*)ga,
                (__attribute__((address_space(3))) void*)(lb + r0 * 64),
                16, 0, 0);
        }
    };

    // ---- prologue: stage tiles 0 and 1; read aLo(0)
    stA(0, 0, 0); stA(0, 1, 0); stB(0, 0, 0); stB(0, 1, 0);
    stA(1, 0, 1); stA(1, 1, 1); stB(1, 0, 1); stB(1, 1, 1);
    VMCNT(8);            // tile 0's 8 loads landed
    BARRIER();

    s16x8 aLo[4][2];
    {
        const unsigned short* hA0 = &ldsA[0][wi][0];
        #pragma unroll
        for (int m = 0; m < 4; ++m) {
            const int rb = (m * 16 + lrow) * 64;
            aLo[m][0] = *(const s16x8*)&hA0[rb + s0];
            aLo[m][1] = *(const s16x8*)&hA0[rb + (s0 ^ 32)];
        }
    }

    for (int t = 0; t < nkt; ++t) {
        const int db = t & 1;
        const unsigned short* hA = &ldsA[db][wi][0];
        const unsigned short* hB = &ldsB[db][bhalf][0];

        s16x8 aHi[4][2], bl[2][2], bh[2][2];

        LGKM0();   // aLo resident (issued at end of prev iter / prologue)
        #pragma unroll
        for (int n = 0; n < 2; ++n) {
            const int rb = (bcol + n * 16 + lrow) * 64;
            bl[n][0] = *(const s16x8*)&hB[rb + s0];
            bl[n][1] = *(const s16x8*)&hB[rb + (s0 ^ 32)];
        }
        #pragma unroll
        for (int n = 0; n < 2; ++n) {
            const int rb = (bcol + (n + 2) * 16 + lrow) * 64;
            bh[n][0] = *(const s16x8*)&hB[rb + s0];
            bh[n][1] = *(const s16x8*)&hB[rb + (s0 ^ 32)];
        }
        __builtin_amdgcn_sched_barrier(0);   // B-reads issue before A-reads
        #pragma unroll
        for (int m = 0; m < 4; ++m) {
            const int rb = ((m + 4) * 16 + lrow) * 64;
            aHi[m][0] = *(const s16x8*)&hA[rb + s0];
            aHi[m][1] = *(const s16x8*)&hA[rb + (s0 ^ 32)];
        }
        LGKM8();   // bl/bh resident; aHi (newest 8) may still be in flight

        __builtin_amdgcn_s_setprio(1);
        #pragma unroll
        for (int m = 0; m < 4; ++m)
            #pragma unroll
            for (int n = 0; n < 2; ++n) {
                acc[m][n]     = __builtin_amdgcn_mfma_f32_16x16x32_bf16(aLo[m][0], bl[n][0], acc[m][n], 0, 0, 0);
                acc[m][n]     = __builtin_amdgcn_mfma_f32_16x16x32_bf16(aLo[m][1], bl[n][1], acc[m][n], 0, 0, 0);
                acc[m][n + 2] = __builtin_amdgcn_mfma_f32_16x16x32_bf16(aLo[m][0], bh[n][0], acc[m][n + 2], 0, 0, 0);
                acc[m][n + 2] = __builtin_amdgcn_mfma_f32_16x16x32_bf16(aLo[m][1], bh[n][1], acc[m][n + 2], 0, 0, 0);
            }
        __builtin_amdgcn_s_setprio(0);
        __builtin_amdgcn_sched_barrier(0);

        LGKM0();       // aHi resident
        BARRIER();     // #1: all waves finished ALL LDS reads of tile t

        if (t + 2 < nkt) {
            stA(db, 0, t + 2); stA(db, 1, t + 2);
            stB(db, 0, t + 2); stB(db, 1, t + 2);
            VMCNT(8);  // S(t+1) landed (16 in flight - 8 newest)
        } else {
            VMCNT(0);  // tail drain
        }
        BARRIER();     // #2: tile t+1 resident everywhere

        if (t + 1 < nkt) {
            const unsigned short* hA2 = &ldsA[db ^ 1][wi][0];
            #pragma unroll
            for (int m = 0; m < 4; ++m) {
                const int rb = (m * 16 + lrow) * 64;
                aLo[m][0] = *(const s16x8*)&hA2[rb + s0];
                aLo[m][1] = *(const s16x8*)&hA2[rb + (s0 ^ 32)];
            }
        }
        __builtin_amdgcn_sched_barrier(0);   // aLo' issues before MFMA2

        __builtin_amdgcn_s_setprio(1);
        #pragma unroll
        for (int m = 0; m < 4; ++m)
            #pragma unroll
            for (int n = 0; n < 2; ++n) {
                acc[m + 4][n]     = __builtin_amdgcn_mfma_f32_16x16x32_bf16(aHi[m][0], bl[n][0], acc[m + 4][n], 0, 0, 0);
                acc[m + 4][n]     = __builtin_amdgcn_mfma_f32_16x16x32_bf16(aHi[m][1], bl[n][1], acc[m + 4][n], 0, 0, 0);
                acc[m + 4][n + 2] = __builtin_amdgcn_mfma_f32_16x16x32_bf16(aHi[m][0], bh[n][0], acc[m + 4][n + 2], 0, 0, 0);
                acc[m + 4][n + 2] = __builtin_amdgcn_mfma_f32_16x16x32_bf16(aHi[m][1], bh[n][1], acc[m + 4][n + 2], 0, 0, 0);
            }
        __builtin_amdgcn_s_setprio(0);
    }

    // ---- epilogue: col=lane&15, row=(lane>>4)*4+reg; n innermost
    const int rowbase = bm + wi * 128 + (kq << 2);
    const int colbase = bn + wj * 64 + lrow;
    float bv[4];
    #pragma unroll
    for (int n = 0; n < 4; ++n) bv[n] = bias[colbase + n * 16];
    #pragma unroll
    for (int m = 0; m < 8; ++m) {
        #pragma unroll
        for (int r = 0; r < 4; ++r) {
            const int rr = rowbase + m * 16 + r;
            #pragma unroll
            for (int n = 0; n < 4; ++n) {
                const int cc = colbase + n * 16;
                const float val = acc[m][n][r] + bv[n];
                if (OUT_BF16)
                    ((unsigned short*)Cv)[(size_t)rr * Nout + cc] = f2bf(val);
                else
                    ((float*)Cv)[(size_t)rr * Nout + cc] = val;
            }
        }
    }
}

// ---------------- attention over B axis: seq=4, batch = N*H ----------------
__global__ __launch_bounds__(64) void attn_kernel(
    const unsigned short* __restrict__ qkv, unsigned short* __restrict__ o)
{
    const int bid  = blockIdx.x;      // n*NH + h
    const int n    = bid >> 4;
    const int h    = bid & 15;
    const int lane = threadIdx.x;
    const int d0   = lane * 2;
    const float scale = 0.0883883476483184405501f;  // 1/sqrt(128)

    float q[4][2], k[4][2], v[4][2];
    #pragma unroll
    for (int b = 0; b < 4; ++b) {
        size_t base = (size_t)(b * NTOK + n) * (3 * ED) + h * HD + d0;
        u16x2 uq = *(const u16x2*)&qkv[base];
        u16x2 uk = *(const u16x2*)&qkv[base + ED];
        u16x2 uv = *(const u16x2*)&qkv[base + 2 * ED];
        q[b][0] = bf2f(uq.x); q[b][1] = bf2f(uq.y);
        k[b][0] = bf2f(uk.x); k[b][1] = bf2f(uk.y);
        v[b][0] = bf2f(uv.x); v[b][1] = bf2f(uv.y);
    }

    float sc[4][4];
    #pragma unroll
    for (int s = 0; s < 4; ++s) {
        #pragma unroll
        for (int t = 0; t < 4; ++t) {
            float p = q[s][0] * k[t][0] + q[s][1] * k[t][1];
            #pragma unroll
            for (int off = 32; off > 0; off >>= 1)
                p += __shfl_xor(p, off, 64);
            sc[s][t] = p * scale;
        }
    }

    #pragma unroll
    for (int s = 0; s < 4; ++s) {
        float mx = fmaxf(fmaxf(sc[s][0], sc[s][1]), fmaxf(sc[s][2], sc[s][3]));
        float e0 = __expf(sc[s][0] - mx);
        float e1 = __expf(sc[s][1] - mx);
        float e2 = __expf(sc[s][2] - mx);
        float e3 = __expf(sc[s][3] - mx);
        float inv = 1.0f / (e0 + e1 + e2 + e3);
        float o0 = (e0 * v[0][0] + e1 * v[1][0] + e2 * v[2][0] + e3 * v[3][0]) * inv;
        float o1 = (e0 * v[0][1] + e1 * v[1][1] + e2 * v[2][1] + e3 * v[3][1]) * inv;
        size_t ob = (size_t)(s * NTOK + n) * ED + h * HD + d0;
        u16x2 ov; ov.x = f2bf(o0); ov.y = f2bf(o1);
        *(u16x2*)&o[ob] = ov;
    }
}

// ---------------- window reverse (LDS transpose) ----------------
__global__ __launch_bounds__(256) void reverse_kernel(const float* __restrict__ o3,
                                                      float* __restrict__ out) {
    __shared__ float lds[16][2052];
    const int t  = threadIdx.x;
    const int b  = blockIdx.x >> 8;
    const int nx = (blockIdx.x >> 4) & 15;
    const int ny = blockIdx.x & 15;
    const int n0 = nx * 256 + ny * 16;

    {
        const int row = t >> 4;
        const int cb  = (t & 15) * 128;
        const float* src = o3 + (size_t)(b * NTOK + n0 + row) * ED + cb;
        #pragma unroll
        for (int i = 0; i < 32; ++i)
            *(f32x4*)&lds[row][cb + i * 4] = *(const f32x4*)&src[i * 4];
    }
    __syncthreads();

    #pragma unroll
    for (int j = 0; j < 2; ++j) {
        const int id = t + j * 256;
        const int py = id & 3, px = (id >> 2) & 3, c = id >> 4;
        const int eb = c * 64 + px * 16 + py * 4;
        f32x4 v[16];
        #pragma unroll
        for (int nz = 0; nz < 16; ++nz)
            v[nz] = *(const f32x4*)&lds[nz][eb];
        float* ob = out + ((size_t)(b * NC + c) * 64 + px * 16 + nx) * 4096
                        + (size_t)(py * 16 + ny) * 64;
        #pragma unroll
        for (int pz = 0; pz < 4; ++pz) {
            float* oz = ob + pz * 16;
            f32x4 w0 = {v[0][pz],  v[1][pz],  v[2][pz],  v[3][pz]};
            f32x4 w1 = {v[4][pz],  v[5][pz],  v[6][pz],  v[7][pz]};
            f32x4 w2 = {v[8][pz],  v[9][pz],  v[10][pz], v[11][pz]};
            f32x4 w3 = {v[12][pz], v[13][pz], v[14][pz], v[15][pz]};
            *(f32x4*)&oz[0]  = w0; *(f32x4*)&oz[4]  = w1;
            *(f32x4*)&oz[8]  = w2; *(f32x4*)&oz[12] = w3;
        }
    }
}

// ---------------------------------------------------------------------------
extern "C" void kernel_launch(void* const* d_in, const int* in_sizes, int n_in,
                              void* d_out, int out_size, void* d_ws, size_t ws_size,
                              hipStream_t stream) {
    const float* x          = (const float*)d_in[0];
    const float* in_proj_w  = (const float*)d_in[1];
    const float* in_proj_b  = (const float*)d_in[2];
    const float* out_proj_w = (const float*)d_in[3];
    const float* out_proj_b = (const float*)d_in[4];
    const float* mlp_w      = (const float*)d_in[5];
    const float* mlp_b      = (const float*)d_in[6];
    float* out = (float*)d_out;

    const size_t M = 16384;                       // B*N rows
    char* ws = (char*)d_ws;
    size_t off = 0;
    unsigned short* tok    = (unsigned short*)(ws + off); off += M * ED * 2;
    unsigned short* w_in   = (unsigned short*)(ws + off); off += (size_t)3 * ED * ED * 2;
    unsigned short* w_mlp  = (unsigned short*)(ws + off); off += (size_t)ED * ED * 2;
    unsigned short* w_outT = (unsigned short*)(ws + off); off += (size_t)ED * ED * 2;
    unsigned short* w_comb = (unsigned short*)(ws + off); off += (size_t)ED * ED * 2;
    float* zbias           = (float*)(ws + off);          off += ED * 4;
    float* b_comb          = (float*)(ws + off);          off += ED * 4;
    unsigned short* obuf   = (unsigned short*)(ws + off); off += M * ED * 2;
    unsigned short* qkv    = (unsigned short*)(ws + off); off += M * 3 * ED * 2;
    float* o3 = (float*)qkv;   // reuse qkv region after attention

    if (ws_size < off) {
        fprintf(stderr, "kernel_launch: ws too small (%zu < %zu)\n", ws_size, off);
        return;
    }

    // weight converts + transpose
    {
        int n4 = 3 * ED * ED / 4;
        f32_to_bf16_kernel<<<(n4 + 255) / 256, 256, 0, stream>>>(in_proj_w, w_in, n4);
        n4 = ED * ED / 4;
        f32_to_bf16_kernel<<<(n4 + 255) / 256, 256, 0, stream>>>(mlp_w, w_mlp, n4);
        transpose_bf16_kernel<<<dim3(ED / 64, ED / 64), 256, 0, stream>>>(
            out_proj_w, w_outT, ED);
        hipMemsetAsync(zbias, 0, ED * sizeof(float), stream);
    }

    // W_comb = mlp_w @ out_proj_w  (row-major [j][k]); 2048^3, 128^2-tile MFMA
    gemm128<<<dim3(ED / 128, ED / 128), 256, 0, stream>>>(
        w_mlp, w_outT, zbias, w_comb, ED, ED, ED);
    // b_comb = mlp_w @ out_proj_b + mlp_b
    bcomb_kernel<<<ED / 256, 256, 0, stream>>>(mlp_w, out_proj_b, mlp_b, b_comb);

    // window partition
    partition_kernel<<<(NB * NC * 64 * 64 * 16) / 256, 256, 0, stream>>>(x, tok);

    // qkv = tok @ in_proj_w^T + in_proj_b   (16384 x 6144 x 2048)
    gemm256<1><<<dim3(64 * (6144 / 256)), 512, 0, stream>>>(
        tok, w_in, in_proj_b, qkv, 16384, 6144, 2048);

    // attention (seq=B=4, batch=N*H)
    attn_kernel<<<NTOK * NH, 64, 0, stream>>>(qkv, obuf);

    // o3 = obuf @ W_comb^T + b_comb  (fused out_proj+mlp, f32 out)
    gemm256<0><<<dim3(64 * (2048 / 256)), 512, 0, stream>>>(
        obuf, w_comb, b_comb, o3, 16384, 2048, 2048);

    // window reverse
    reverse_kernel<<<NB * 16 * 16, 256, 0, stream>>>(o3, out);
}

// Round 6
// 823.573 us; speedup vs baseline: 1.1954x; 1.1954x over previous
//
#include <hip/hip_runtime.h>
#include <stdio.h>

// ---------------------------------------------------------------------------
// WindowAttention: partition -> QKV gemm -> tiny attention over B axis ->
// fused (out_proj @ mlp) gemm -> reverse.
// GEMM: 256x256 bf16 MFMA, 4 quadrant phases per K-tile separated by
// sched_barrier seams (reads of q_{i+1} issue while q_i's MFMAs drain the
// matrix pipe); exactly 2 barriers/tile at the staging-hazard points.
// ---------------------------------------------------------------------------

typedef __attribute__((ext_vector_type(4))) float f32x4;
typedef __attribute__((ext_vector_type(8))) short s16x8;
typedef __attribute__((ext_vector_type(2))) unsigned short u16x2;
typedef __attribute__((ext_vector_type(4))) unsigned short u16x4;

#define NB 4        // batch B (attention seq len)
#define NC 32       // channels
#define NTOK 4096   // N = 16^3 windows
#define ED 2048     // embed dim E
#define NH 16       // heads
#define HD 128      // head dim

__device__ __forceinline__ unsigned short f2bf(float f) {
    union { float f; unsigned int u; } v; v.f = f;
    unsigned int r = (v.u + 0x7fffu + ((v.u >> 16) & 1u)) >> 16;
    return (unsigned short)r;
}
__device__ __forceinline__ float bf2f(unsigned short u) {
    union { unsigned int u; float f; } v; v.u = ((unsigned int)u) << 16;
    return v.f;
}

#define BARRIER() asm volatile("s_barrier" ::: "memory")
#define LGKM0() do { asm volatile("s_waitcnt lgkmcnt(0)" ::: "memory"); \
                     __builtin_amdgcn_sched_barrier(0); } while (0)
#define VMCNT(n) asm volatile("s_waitcnt vmcnt(" #n ")" ::: "memory")
#define SEAM() __builtin_amdgcn_sched_barrier(0)

// ---------------- fp32 -> bf16 convert (weights) ----------------
__global__ void f32_to_bf16_kernel(const float* __restrict__ src,
                                   unsigned short* __restrict__ dst, int n4) {
    int i = blockIdx.x * blockDim.x + threadIdx.x;
    if (i >= n4) return;
    f32x4 v = *(const f32x4*)(src + (size_t)i * 4);
    u16x4 w;
    w.x = f2bf(v.x); w.y = f2bf(v.y); w.z = f2bf(v.z); w.w = f2bf(v.w);
    *(u16x4*)(dst + (size_t)i * 4) = w;
}

// ---------------- transpose f32 -> bf16: dst[j,k] = src[k,j] ----------------
__global__ __launch_bounds__(256) void transpose_bf16_kernel(
    const float* __restrict__ src, unsigned short* __restrict__ dst, int n) {
    __shared__ float lds[64][68];
    const int bx = blockIdx.x * 64;   // j base
    const int by = blockIdx.y * 64;   // k base
    const int t  = threadIdx.x;
    const int r  = t >> 2;            // 0..63
    const int c4 = (t & 3) * 16;      // 0/16/32/48
    const float* s = src + (size_t)(by + r) * n + bx + c4;
    #pragma unroll
    for (int i = 0; i < 4; ++i)
        *(f32x4*)&lds[r][c4 + i * 4] = *(const f32x4*)(s + i * 4);
    __syncthreads();
    unsigned short* d = dst + (size_t)(bx + r) * n + by + c4;
    #pragma unroll
    for (int i = 0; i < 4; ++i) {
        u16x4 w;
        w.x = f2bf(lds[c4 + i * 4 + 0][r]);
        w.y = f2bf(lds[c4 + i * 4 + 1][r]);
        w.z = f2bf(lds[c4 + i * 4 + 2][r]);
        w.w = f2bf(lds[c4 + i * 4 + 3][r]);
        *(u16x4*)(d + i * 4) = w;
    }
}

// ---------------- b_comb = mlp_w @ out_proj_b + mlp_b (wave per row) -------
__global__ __launch_bounds__(256) void bcomb_kernel(
    const float* __restrict__ mlp_w, const float* __restrict__ opb,
    const float* __restrict__ mlpb, float* __restrict__ bcomb) {
    const int wave = threadIdx.x >> 6, lane = threadIdx.x & 63;
    const int row = blockIdx.x * 4 + wave;
    const float* r = mlp_w + (size_t)row * ED;
    float s = 0.0f;
    for (int k = lane * 4; k < ED; k += 256) {
        f32x4 a = *(const f32x4*)(r + k);
        f32x4 b = *(const f32x4*)(opb + k);
        s += a.x * b.x + a.y * b.y + a.z * b.z + a.w * b.w;
    }
    #pragma unroll
    for (int off = 32; off > 0; off >>= 1) s += __shfl_xor(s, off, 64);
    if (lane == 0) bcomb[row] = s + mlpb[row];
}

// ---------------- window partition: x -> tok (B,N,E) bf16 ----------------
__global__ void partition_kernel(const float* __restrict__ x,
                                 unsigned short* __restrict__ tok) {
    int idx = blockIdx.x * blockDim.x + threadIdx.x;
    int m = idx & 15;
    int t = idx >> 4;
    int Y = t & 63; t >>= 6;
    int X = t & 63; t >>= 6;
    int c = t & 31;
    int b = t >> 5;
    f32x4 xv = *(const f32x4*)(x + (size_t)idx * 4);
    int nx = X >> 2, px = X & 3;
    int ny = Y >> 2, py = Y & 3;
    int n = nx * 256 + ny * 16 + m;
    int e = c * 64 + px * 16 + py * 4;
    size_t dst = (size_t)(b * NTOK + n) * ED + e;
    u16x4 w;
    w.x = f2bf(xv.x); w.y = f2bf(xv.y); w.z = f2bf(xv.z); w.w = f2bf(xv.w);
    *(u16x4*)&tok[dst] = w;
}

// ---------------- 128x128 4-wave bf16 GEMM (for small W_comb job) ----------
__global__ __launch_bounds__(256) void gemm128(
    const unsigned short* __restrict__ A,   // M x K bf16
    const unsigned short* __restrict__ W,   // Nout x K bf16
    const float* __restrict__ bias,         // Nout f32
    unsigned short* __restrict__ C,         // M x Nout bf16
    int M, int Nout, int K)
{
    __shared__ unsigned short ldsA[128 * 64];
    __shared__ unsigned short ldsW[128 * 64];

    const int tid  = threadIdx.x;
    const int wave = tid >> 6;
    const int lane = tid & 63;
    const int bm = blockIdx.x * 128;
    const int bn = blockIdx.y * 128;
    const int wm = (wave >> 1) * 64;
    const int wn = (wave & 1) * 64;

    f32x4 acc[4][4] = {};

    const int srow = lane >> 3;
    const int scol = (lane & 7) * 8;
    const int lrow = lane & 15;
    const int lk   = (lane >> 4) * 8;

    const int nkt = K >> 6;
    for (int kt = 0; kt < nkt; ++kt) {
        const int kbase = kt * 64;
        #pragma unroll
        for (int q = 0; q < 4; ++q) {
            int chunk = wave * 4 + q;
            int row = chunk * 8 + srow;
            const unsigned short* ga = A + (size_t)(bm + row) * K + kbase + scol;
            const unsigned short* gw = W + (size_t)(bn + row) * K + kbase + scol;
            __builtin_amdgcn_global_load_lds(
                (const __attribute__((address_space(1))) void*)ga,
                (__attribute__((address_space(3))) void*)(&ldsA[chunk * 512]),
                16, 0, 0);
            __builtin_amdgcn_global_load_lds(
                (const __attribute__((address_space(1))) void*)gw,
                (__attribute__((address_space(3))) void*)(&ldsW[chunk * 512]),
                16, 0, 0);
        }
        __syncthreads();

        #pragma unroll
        for (int ks = 0; ks < 2; ++ks) {
            const int k0 = ks * 32 + lk;
            s16x8 af[4], bf[4];
            #pragma unroll
            for (int m = 0; m < 4; ++m)
                af[m] = *(const s16x8*)&ldsA[(wm + m * 16 + lrow) * 64 + k0];
            #pragma unroll
            for (int n = 0; n < 4; ++n)
                bf[n] = *(const s16x8*)&ldsW[(wn + n * 16 + lrow) * 64 + k0];
            #pragma unroll
            for (int m = 0; m < 4; ++m)
                #pragma unroll
                for (int n = 0; n < 4; ++n)
                    acc[m][n] = __builtin_amdgcn_mfma_f32_16x16x32_bf16(
                        af[m], bf[n], acc[m][n], 0, 0, 0);
        }
        __syncthreads();
    }

    const int col   = lane & 15;
    const int rbase = (lane >> 4) * 4;
    #pragma unroll
    for (int n = 0; n < 4; ++n) {
        int cc = bn + wn + n * 16 + col;
        float bv = bias[cc];
        #pragma unroll
        for (int m = 0; m < 4; ++m)
            #pragma unroll
            for (int r = 0; r < 4; ++r) {
                int rr = bm + wm + m * 16 + rbase + r;
                C[(size_t)rr * Nout + cc] = f2bf(acc[m][n][r] + bv);
            }
    }
}

// ---------------- 256x256 quadrant-pipelined bf16 GEMM ----------------
// C[r,j] = sum_k A[r,k] * W[j,k] + bias[j].  Requires M == 16384 and
// Nout % 1024 == 0.  8 waves (2M x 4N), per-wave 128x64, BK=64, LDS 128KB.
// Per K-tile t (buf db=t&1), 4 quadrant phases, 2 barriers:
//  q1: read aLo(8)+bl(4); stage B(t+1)->db^1; MFMA m0-3 x n0-1
//  q2: read bh(4);                            MFMA m0-3 x n2-3
//  q3: read aHi(8); LGKM0; BARRIER; stage A(t+2)->db; MFMA m4-7 x n2-3
//  q4:                                        MFMA m4-7 x n0-1
//      VMCNT(4) [newest 4 = A(t+2); B(t+1),A(t+1) landed]; BARRIER
// Compiler inserts counted lgkm waits for ds_read->MFMA; q_{i+1} reads issue
// while q_i MFMAs drain the matrix pipe. sched_barrier(0) seams stop
// cross-quadrant read hoisting only.
template <int OUT_BF16>
__global__ __launch_bounds__(512, 2) void gemm256(
    const unsigned short* __restrict__ A,   // M x K bf16
    const unsigned short* __restrict__ W,   // Nout x K bf16
    const float* __restrict__ bias,         // Nout f32
    void* __restrict__ Cv,                  // M x Nout (bf16 or f32)
    int M, int Nout, int K)
{
    __shared__ unsigned short ldsA[2][2][128 * 64];
    __shared__ unsigned short ldsB[2][2][128 * 64];

    const int tid  = threadIdx.x;
    const int wave = tid >> 6;
    const int lane = tid & 63;

    // L2-locality mapping (bijective, gm=64): XCD x owns m-band x; 8m x 4n
    // macro-tiles of 32 blocks = the concurrent set per XCD.
    const int f   = blockIdx.x;
    const int xcd = f & 7;
    const int r_  = f >> 3;
    const int mac = r_ >> 5;
    const int w_  = r_ & 31;
    const int bm  = (xcd * 8 + (w_ & 7)) * 256;
    const int bn  = (mac * 4 + (w_ >> 3)) * 256;

    const int wi    = wave >> 2;        // 0/1: M half
    const int wj    = wave & 3;         // 0-3: N quarter
    const int bhalf = wj >> 1;          // B half this wave reads
    const int bcol  = (wj & 1) * 64;    // col base within that half

    const int lrow = lane & 15;
    const int kq   = lane >> 4;                    // 0-3
    const int s0   = ((kq ^ (lrow & 7)) << 3);     // swizzled elem offset

    f32x4 acc[8][4] = {};

    const int nkt = K >> 6;

    const int srl   = lane >> 3;                         // 0-7
    const int sslot = (((lane & 7) ^ srl) << 3);         // pre-swizzled src off

    auto stA = [&](int db, int half, int tt) {
        const unsigned short* gb = A + (size_t)(bm + half * 128) * K + tt * 64;
        unsigned short* lb = &ldsA[db][half][0];
        #pragma unroll
        for (int q = 0; q < 2; ++q) {
            const int r0 = wave * 16 + q * 8;
            const unsigned short* ga = gb + (size_t)(r0 + srl) * K + sslot;
            __builtin_amdgcn_global_load_lds(
                (const __attribute__((address_space(1))) void*)ga,
                (__attribute__((address_space(3))) void*)(lb + r0 * 64),
                16, 0, 0);
        }
    };
    auto stB = [&](int db, int half, int tt) {
        const unsigned short* gb = W + (size_t)(bn + half * 128) * K + tt * 64;
        unsigned short* lb = &ldsB[db][half][0];
        #pragma unroll
        for (int q = 0; q < 2; ++q) {
            const int r0 = wave * 16 + q * 8;
            const unsigned short* ga = gb + (size_t)(r0 + srl) * K + sslot;
            __builtin_amdgcn_global_load_lds(
                (const __attribute__((address_space(1))) void*)ga,
                (__attribute__((address_space(3))) void*)(lb + r0 * 64),
                16, 0, 0);
        }
    };

    // ---- prologue: A(0), B(0) -> buf0; A(1) -> buf1. B(1) staged in t0/q1.
    stA(0, 0, 0); stA(0, 1, 0);
    stB(0, 0, 0); stB(0, 1, 0);
    stA(1, 0, 1); stA(1, 1, 1);
    VMCNT(4);            // A(0), B(0) landed; A(1) may ride
    BARRIER();

    for (int t = 0; t < nkt; ++t) {
        const int db = t & 1;
        const unsigned short* hA = &ldsA[db][wi][0];
        const unsigned short* hB = &ldsB[db][bhalf][0];

        s16x8 aLo[4][2], aHi[4][2], bl[2][2], bh[2][2];

        // ===== q1: read aLo + bl; stage B(t+1) -> db^1; MFMA (m0-3, n0-1)
        #pragma unroll
        for (int m = 0; m < 4; ++m) {
            const int rb = (m * 16 + lrow) * 64;
            aLo[m][0] = *(const s16x8*)&hA[rb + s0];
            aLo[m][1] = *(const s16x8*)&hA[rb + (s0 ^ 32)];
        }
        #pragma unroll
        for (int n = 0; n < 2; ++n) {
            const int rb = (bcol + n * 16 + lrow) * 64;
            bl[n][0] = *(const s16x8*)&hB[rb + s0];
            bl[n][1] = *(const s16x8*)&hB[rb + (s0 ^ 32)];
        }
        if (t + 1 < nkt) { stB(db ^ 1, 0, t + 1); stB(db ^ 1, 1, t + 1); }
        SEAM();
        __builtin_amdgcn_s_setprio(1);
        #pragma unroll
        for (int m = 0; m < 4; ++m)
            #pragma unroll
            for (int n = 0; n < 2; ++n) {
                acc[m][n] = __builtin_amdgcn_mfma_f32_16x16x32_bf16(aLo[m][0], bl[n][0], acc[m][n], 0, 0, 0);
                acc[m][n] = __builtin_amdgcn_mfma_f32_16x16x32_bf16(aLo[m][1], bl[n][1], acc[m][n], 0, 0, 0);
            }
        __builtin_amdgcn_s_setprio(0);
        SEAM();

        // ===== q2: read bh; MFMA (m0-3, n2-3)  [reads hide under q1 drain]
        #pragma unroll
        for (int n = 0; n < 2; ++n) {
            const int rb = (bcol + (n + 2) * 16 + lrow) * 64;
            bh[n][0] = *(const s16x8*)&hB[rb + s0];
            bh[n][1] = *(const s16x8*)&hB[rb + (s0 ^ 32)];
        }
        __builtin_amdgcn_s_setprio(1);
        #pragma unroll
        for (int m = 0; m < 4; ++m)
            #pragma unroll
            for (int n = 0; n < 2; ++n) {
                acc[m][n + 2] = __builtin_amdgcn_mfma_f32_16x16x32_bf16(aLo[m][0], bh[n][0], acc[m][n + 2], 0, 0, 0);
                acc[m][n + 2] = __builtin_amdgcn_mfma_f32_16x16x32_bf16(aLo[m][1], bh[n][1], acc[m][n + 2], 0, 0, 0);
            }
        __builtin_amdgcn_s_setprio(0);
        SEAM();

        // ===== q3: read aHi; drain + barrier; stage A(t+2) -> db; MFMA
        #pragma unroll
        for (int m = 0; m < 4; ++m) {
            const int rb = ((m + 4) * 16 + lrow) * 64;
            aHi[m][0] = *(const s16x8*)&hA[rb + s0];
            aHi[m][1] = *(const s16x8*)&hA[rb + (s0 ^ 32)];
        }
        LGKM0();       // all this tile's LDS reads complete (per wave)
        BARRIER();     // #1: every wave done reading buffers of tile t
        if (t + 2 < nkt) { stA(db, 0, t + 2); stA(db, 1, t + 2); }
        __builtin_amdgcn_s_setprio(1);
        #pragma unroll
        for (int m = 0; m < 4; ++m)
            #pragma unroll
            for (int n = 0; n < 2; ++n) {
                acc[m + 4][n + 2] = __builtin_amdgcn_mfma_f32_16x16x32_bf16(aHi[m][0], bh[n][0], acc[m + 4][n + 2], 0, 0, 0);
                acc[m + 4][n + 2] = __builtin_amdgcn_mfma_f32_16x16x32_bf16(aHi[m][1], bh[n][1], acc[m + 4][n + 2], 0, 0, 0);
            }
        __builtin_amdgcn_s_setprio(0);
        SEAM();

        // ===== q4: MFMA (m4-7, n0-1); counted vmcnt; barrier
        __builtin_amdgcn_s_setprio(1);
        #pragma unroll
        for (int m = 0; m < 4; ++m)
            #pragma unroll
            for (int n = 0; n < 2; ++n) {
                acc[m + 4][n] = __builtin_amdgcn_mfma_f32_16x16x32_bf16(aHi[m][0], bl[n][0], acc[m + 4][n], 0, 0, 0);
                acc[m + 4][n] = __builtin_amdgcn_mfma_f32_16x16x32_bf16(aHi[m][1], bl[n][1], acc[m + 4][n], 0, 0, 0);
            }
        __builtin_amdgcn_s_setprio(0);
        if (t + 2 < nkt)      { VMCNT(4); }   // only A(t+2) may ride
        else                  { VMCNT(0); }   // tail drain
        BARRIER();     // #2: tile t+1 resident everywhere
    }

    // ---- epilogue: col=lane&15, row=(lane>>4)*4+reg; n innermost
    const int rowbase = bm + wi * 128 + (kq << 2);
    const int colbase = bn + wj * 64 + lrow;
    float bv[4];
    #pragma unroll
    for (int n = 0; n < 4; ++n) bv[n] = bias[colbase + n * 16];
    #pragma unroll
    for (int m = 0; m < 8; ++m) {
        #pragma unroll
        for (int r = 0; r < 4; ++r) {
            const int rr = rowbase + m * 16 + r;
            #pragma unroll
            for (int n = 0; n < 4; ++n) {
                const int cc = colbase + n * 16;
                const float val = acc[m][n][r] + bv[n];
                if (OUT_BF16)
                    ((unsigned short*)Cv)[(size_t)rr * Nout + cc] = f2bf(val);
                else
                    ((float*)Cv)[(size_t)rr * Nout + cc] = val;
            }
        }
    }
}

// ---------------- attention over B axis: seq=4, batch = N*H ----------------
__global__ __launch_bounds__(64) void attn_kernel(
    const unsigned short* __restrict__ qkv, unsigned short* __restrict__ o)
{
    const int bid  = blockIdx.x;      // n*NH + h
    const int n    = bid >> 4;
    const int h    = bid & 15;
    const int lane = threadIdx.x;
    const int d0   = lane * 2;
    const float scale = 0.0883883476483184405501f;  // 1/sqrt(128)

    float q[4][2], k[4][2], v[4][2];
    #pragma unroll
    for (int b = 0; b < 4; ++b) {
        size_t base = (size_t)(b * NTOK + n) * (3 * ED) + h * HD + d0;
        u16x2 uq = *(const u16x2*)&qkv[base];
        u16x2 uk = *(const u16x2*)&qkv[base + ED];
        u16x2 uv = *(const u16x2*)&qkv[base + 2 * ED];
        q[b][0] = bf2f(uq.x); q[b][1] = bf2f(uq.y);
        k[b][0] = bf2f(uk.x); k[b][1] = bf2f(uk.y);
        v[b][0] = bf2f(uv.x); v[b][1] = bf2f(uv.y);
    }

    float sc[4][4];
    #pragma unroll
    for (int s = 0; s < 4; ++s) {
        #pragma unroll
        for (int t = 0; t < 4; ++t) {
            float p = q[s][0] * k[t][0] + q[s][1] * k[t][1];
            #pragma unroll
            for (int off = 32; off > 0; off >>= 1)
                p += __shfl_xor(p, off, 64);
            sc[s][t] = p * scale;
        }
    }

    #pragma unroll
    for (int s = 0; s < 4; ++s) {
        float mx = fmaxf(fmaxf(sc[s][0], sc[s][1]), fmaxf(sc[s][2], sc[s][3]));
        float e0 = __expf(sc[s][0] - mx);
        float e1 = __expf(sc[s][1] - mx);
        float e2 = __expf(sc[s][2] - mx);
        float e3 = __expf(sc[s][3] - mx);
        float inv = 1.0f / (e0 + e1 + e2 + e3);
        float o0 = (e0 * v[0][0] + e1 * v[1][0] + e2 * v[2][0] + e3 * v[3][0]) * inv;
        float o1 = (e0 * v[0][1] + e1 * v[1][1] + e2 * v[2][1] + e3 * v[3][1]) * inv;
        size_t ob = (size_t)(s * NTOK + n) * ED + h * HD + d0;
        u16x2 ov; ov.x = f2bf(o0); ov.y = f2bf(o1);
        *(u16x2*)&o[ob] = ov;
    }
}

// ---------------- window reverse (LDS transpose) ----------------
__global__ __launch_bounds__(256) void reverse_kernel(const float* __restrict__ o3,
                                                      float* __restrict__ out) {
    __shared__ float lds[16][2052];
    const int t  = threadIdx.x;
    const int b  = blockIdx.x >> 8;
    const int nx = (blockIdx.x >> 4) & 15;
    const int ny = blockIdx.x & 15;
    const int n0 = nx * 256 + ny * 16;

    {
        const int row = t >> 4;
        const int cb  = (t & 15) * 128;
        const float* src = o3 + (size_t)(b * NTOK + n0 + row) * ED + cb;
        #pragma unroll
        for (int i = 0; i < 32; ++i)
            *(f32x4*)&lds[row][cb + i * 4] = *(const f32x4*)&src[i * 4];
    }
    __syncthreads();

    #pragma unroll
    for (int j = 0; j < 2; ++j) {
        const int id = t + j * 256;
        const int py = id & 3, px = (id >> 2) & 3, c = id >> 4;
        const int eb = c * 64 + px * 16 + py * 4;
        f32x4 v[16];
        #pragma unroll
        for (int nz = 0; nz < 16; ++nz)
            v[nz] = *(const f32x4*)&lds[nz][eb];
        float* ob = out + ((size_t)(b * NC + c) * 64 + px * 16 + nx) * 4096
                        + (size_t)(py * 16 + ny) * 64;
        #pragma unroll
        for (int pz = 0; pz < 4; ++pz) {
            float* oz = ob + pz * 16;
            f32x4 w0 = {v[0][pz],  v[1][pz],  v[2][pz],  v[3][pz]};
            f32x4 w1 = {v[4][pz],  v[5][pz],  v[6][pz],  v[7][pz]};
            f32x4 w2 = {v[8][pz],  v[9][pz],  v[10][pz], v[11][pz]};
            f32x4 w3 = {v[12][pz], v[13][pz], v[14][pz], v[15][pz]};
            *(f32x4*)&oz[0]  = w0; *(f32x4*)&oz[4]  = w1;
            *(f32x4*)&oz[8]  = w2; *(f32x4*)&oz[12] = w3;
        }
    }
}

// ---------------------------------------------------------------------------
extern "C" void kernel_launch(void* const* d_in, const int* in_sizes, int n_in,
                              void* d_out, int out_size, void* d_ws, size_t ws_size,
                              hipStream_t stream) {
    const float* x          = (const float*)d_in[0];
    const float* in_proj_w  = (const float*)d_in[1];
    const float* in_proj_b  = (const float*)d_in[2];
    const float* out_proj_w = (const float*)d_in[3];
    const float* out_proj_b = (const float*)d_in[4];
    const float* mlp_w      = (const float*)d_in[5];
    const float* mlp_b      = (const float*)d_in[6];
    float* out = (float*)d_out;

    const size_t M = 16384;                       // B*N rows
    char* ws = (char*)d_ws;
    size_t off = 0;
    unsigned short* tok    = (unsigned short*)(ws + off); off += M * ED * 2;
    unsigned short* w_in   = (unsigned short*)(ws + off); off += (size_t)3 * ED * ED * 2;
    unsigned short* w_mlp  = (unsigned short*)(ws + off); off += (size_t)ED * ED * 2;
    unsigned short* w_outT = (unsigned short*)(ws + off); off += (size_t)ED * ED * 2;
    unsigned short* w_comb = (unsigned short*)(ws + off); off += (size_t)ED * ED * 2;
    float* zbias           = (float*)(ws + off);          off += ED * 4;
    float* b_comb          = (float*)(ws + off);          off += ED * 4;
    unsigned short* obuf   = (unsigned short*)(ws + off); off += M * ED * 2;
    unsigned short* qkv    = (unsigned short*)(ws + off); off += M * 3 * ED * 2;
    float* o3 = (float*)qkv;   // reuse qkv region after attention

    if (ws_size < off) {
        fprintf(stderr, "kernel_launch: ws too small (%zu < %zu)\n", ws_size, off);
        return;
    }

    // weight converts + transpose
    {
        int n4 = 3 * ED * ED / 4;
        f32_to_bf16_kernel<<<(n4 + 255) / 256, 256, 0, stream>>>(in_proj_w, w_in, n4);
        n4 = ED * ED / 4;
        f32_to_bf16_kernel<<<(n4 + 255) / 256, 256, 0, stream>>>(mlp_w, w_mlp, n4);
        transpose_bf16_kernel<<<dim3(ED / 64, ED / 64), 256, 0, stream>>>(
            out_proj_w, w_outT, ED);
        hipMemsetAsync(zbias, 0, ED * sizeof(float), stream);
    }

    // W_comb = mlp_w @ out_proj_w  (row-major [j][k]); 2048^3, 128^2-tile MFMA
    gemm128<<<dim3(ED / 128, ED / 128), 256, 0, stream>>>(
        w_mlp, w_outT, zbias, w_comb, ED, ED, ED);
    // b_comb = mlp_w @ out_proj_b + mlp_b
    bcomb_kernel<<<ED / 4, 256, 0, stream>>>(mlp_w, out_proj_b, mlp_b, b_comb);

    // window partition
    partition_kernel<<<(NB * NC * 64 * 64 * 16) / 256, 256, 0, stream>>>(x, tok);

    // qkv = tok @ in_proj_w^T + in_proj_b   (16384 x 6144 x 2048)
    gemm256<1><<<dim3(64 * (6144 / 256)), 512, 0, stream>>>(
        tok, w_in, in_proj_b, qkv, 16384, 6144, 2048);

    // attention (seq=B=4, batch=N*H)
    attn_kernel<<<NTOK * NH, 64, 0, stream>>>(qkv, obuf);

    // o3 = obuf @ W_comb^T + b_comb  (fused out_proj+mlp, f32 out)
    gemm256<0><<<dim3(64 * (2048 / 256)), 512, 0, stream>>>(
        obuf, w_comb, b_comb, o3, 16384, 2048, 2048);

    // window reverse
    reverse_kernel<<<NB * 16 * 16, 256, 0, stream>>>(o3, out);
}

// Round 7
// 666.691 us; speedup vs baseline: 1.4767x; 1.2353x over previous
//
#include <hip/hip_runtime.h>
#include <stdio.h>

// ---------------------------------------------------------------------------
// WindowAttention: partition -> QKV gemm -> attention over B axis ->
// fused (out_proj @ mlp) gemm with window-reverse scatter epilogue.
// GEMM: round-4 2-region 256x256 bf16 MFMA structure (best measured: 46%).
// ---------------------------------------------------------------------------

typedef __attribute__((ext_vector_type(4))) float f32x4;
typedef __attribute__((ext_vector_type(8))) short s16x8;
typedef __attribute__((ext_vector_type(2))) unsigned short u16x2;
typedef __attribute__((ext_vector_type(4))) unsigned short u16x4;

#define NB 4        // batch B (attention seq len)
#define NC 32       // channels
#define NTOK 4096   // N = 16^3 windows
#define ED 2048     // embed dim E
#define NH 16       // heads
#define HD 128      // head dim

__device__ __forceinline__ unsigned short f2bf(float f) {
    union { float f; unsigned int u; } v; v.f = f;
    unsigned int r = (v.u + 0x7fffu + ((v.u >> 16) & 1u)) >> 16;
    return (unsigned short)r;
}
__device__ __forceinline__ float bf2f(unsigned short u) {
    union { unsigned int u; float f; } v; v.u = ((unsigned int)u) << 16;
    return v.f;
}

#define BARRIER() asm volatile("s_barrier" ::: "memory")
#define LGKM0() do { asm volatile("s_waitcnt lgkmcnt(0)" ::: "memory"); \
                     __builtin_amdgcn_sched_barrier(0); } while (0)
#define VMCNT(n) asm volatile("s_waitcnt vmcnt(" #n ")" ::: "memory")

// ---------------- fp32 -> bf16 convert (weights) ----------------
__global__ void f32_to_bf16_kernel(const float* __restrict__ src,
                                   unsigned short* __restrict__ dst, int n4) {
    int i = blockIdx.x * blockDim.x + threadIdx.x;
    if (i >= n4) return;
    f32x4 v = *(const f32x4*)(src + (size_t)i * 4);
    u16x4 w;
    w.x = f2bf(v.x); w.y = f2bf(v.y); w.z = f2bf(v.z); w.w = f2bf(v.w);
    *(u16x4*)(dst + (size_t)i * 4) = w;
}

// ---------------- transpose f32 -> bf16: dst[j,k] = src[k,j] ----------------
__global__ __launch_bounds__(256) void transpose_bf16_kernel(
    const float* __restrict__ src, unsigned short* __restrict__ dst, int n) {
    __shared__ float lds[64][68];
    const int bx = blockIdx.x * 64;   // j base
    const int by = blockIdx.y * 64;   // k base
    const int t  = threadIdx.x;
    const int r  = t >> 2;            // 0..63
    const int c4 = (t & 3) * 16;      // 0/16/32/48
    const float* s = src + (size_t)(by + r) * n + bx + c4;
    #pragma unroll
    for (int i = 0; i < 4; ++i)
        *(f32x4*)&lds[r][c4 + i * 4] = *(const f32x4*)(s + i * 4);
    __syncthreads();
    unsigned short* d = dst + (size_t)(bx + r) * n + by + c4;
    #pragma unroll
    for (int i = 0; i < 4; ++i) {
        u16x4 w;
        w.x = f2bf(lds[c4 + i * 4 + 0][r]);
        w.y = f2bf(lds[c4 + i * 4 + 1][r]);
        w.z = f2bf(lds[c4 + i * 4 + 2][r]);
        w.w = f2bf(lds[c4 + i * 4 + 3][r]);
        *(u16x4*)(d + i * 4) = w;
    }
}

// ---------------- b_comb = mlp_w @ out_proj_b + mlp_b (wave per row) -------
__global__ __launch_bounds__(256) void bcomb_kernel(
    const float* __restrict__ mlp_w, const float* __restrict__ opb,
    const float* __restrict__ mlpb, float* __restrict__ bcomb) {
    const int wave = threadIdx.x >> 6, lane = threadIdx.x & 63;
    const int row = blockIdx.x * 4 + wave;
    const float* r = mlp_w + (size_t)row * ED;
    float s = 0.0f;
    for (int k = lane * 4; k < ED; k += 256) {
        f32x4 a = *(const f32x4*)(r + k);
        f32x4 b = *(const f32x4*)(opb + k);
        s += a.x * b.x + a.y * b.y + a.z * b.z + a.w * b.w;
    }
    #pragma unroll
    for (int off = 32; off > 0; off >>= 1) s += __shfl_xor(s, off, 64);
    if (lane == 0) bcomb[row] = s + mlpb[row];
}

// ---------------- window partition: x -> tok (B,N,E) bf16 ----------------
__global__ void partition_kernel(const float* __restrict__ x,
                                 unsigned short* __restrict__ tok) {
    int idx = blockIdx.x * blockDim.x + threadIdx.x;
    int m = idx & 15;
    int t = idx >> 4;
    int Y = t & 63; t >>= 6;
    int X = t & 63; t >>= 6;
    int c = t & 31;
    int b = t >> 5;
    f32x4 xv = *(const f32x4*)(x + (size_t)idx * 4);
    int nx = X >> 2, px = X & 3;
    int ny = Y >> 2, py = Y & 3;
    int n = nx * 256 + ny * 16 + m;
    int e = c * 64 + px * 16 + py * 4;
    size_t dst = (size_t)(b * NTOK + n) * ED + e;
    u16x4 w;
    w.x = f2bf(xv.x); w.y = f2bf(xv.y); w.z = f2bf(xv.z); w.w = f2bf(xv.w);
    *(u16x4*)&tok[dst] = w;
}

// ---------------- 128x128 4-wave bf16 GEMM (for small W_comb job) ----------
__global__ __launch_bounds__(256) void gemm128(
    const unsigned short* __restrict__ A,   // M x K bf16
    const unsigned short* __restrict__ W,   // Nout x K bf16
    const float* __restrict__ bias,         // Nout f32
    unsigned short* __restrict__ C,         // M x Nout bf16
    int M, int Nout, int K)
{
    __shared__ unsigned short ldsA[128 * 64];
    __shared__ unsigned short ldsW[128 * 64];

    const int tid  = threadIdx.x;
    const int wave = tid >> 6;
    const int lane = tid & 63;
    const int bm = blockIdx.x * 128;
    const int bn = blockIdx.y * 128;
    const int wm = (wave >> 1) * 64;
    const int wn = (wave & 1) * 64;

    f32x4 acc[4][4] = {};

    const int srow = lane >> 3;
    const int scol = (lane & 7) * 8;
    const int lrow = lane & 15;
    const int lk   = (lane >> 4) * 8;

    const int nkt = K >> 6;
    for (int kt = 0; kt < nkt; ++kt) {
        const int kbase = kt * 64;
        #pragma unroll
        for (int q = 0; q < 4; ++q) {
            int chunk = wave * 4 + q;
            int row = chunk * 8 + srow;
            const unsigned short* ga = A + (size_t)(bm + row) * K + kbase + scol;
            const unsigned short* gw = W + (size_t)(bn + row) * K + kbase + scol;
            __builtin_amdgcn_global_load_lds(
                (const __attribute__((address_space(1))) void*)ga,
                (__attribute__((address_space(3))) void*)(&ldsA[chunk * 512]),
                16, 0, 0);
            __builtin_amdgcn_global_load_lds(
                (const __attribute__((address_space(1))) void*)gw,
                (__attribute__((address_space(3))) void*)(&ldsW[chunk * 512]),
                16, 0, 0);
        }
        __syncthreads();

        #pragma unroll
        for (int ks = 0; ks < 2; ++ks) {
            const int k0 = ks * 32 + lk;
            s16x8 af[4], bf[4];
            #pragma unroll
            for (int m = 0; m < 4; ++m)
                af[m] = *(const s16x8*)&ldsA[(wm + m * 16 + lrow) * 64 + k0];
            #pragma unroll
            for (int n = 0; n < 4; ++n)
                bf[n] = *(const s16x8*)&ldsW[(wn + n * 16 + lrow) * 64 + k0];
            #pragma unroll
            for (int m = 0; m < 4; ++m)
                #pragma unroll
                for (int n = 0; n < 4; ++n)
                    acc[m][n] = __builtin_amdgcn_mfma_f32_16x16x32_bf16(
                        af[m], bf[n], acc[m][n], 0, 0, 0);
        }
        __syncthreads();
    }

    const int col   = lane & 15;
    const int rbase = (lane >> 4) * 4;
    #pragma unroll
    for (int n = 0; n < 4; ++n) {
        int cc = bn + wn + n * 16 + col;
        float bv = bias[cc];
        #pragma unroll
        for (int m = 0; m < 4; ++m)
            #pragma unroll
            for (int r = 0; r < 4; ++r) {
                int rr = bm + wm + m * 16 + rbase + r;
                C[(size_t)rr * Nout + cc] = f2bf(acc[m][n][r] + bv);
            }
    }
}

// ---------------- 256x256 2-region bf16 GEMM (round-4 structure) ----------
// C[r,j] = sum_k A[r,k] * W[j,k] + bias[j].  Requires M == 16384 and
// Nout % 1024 == 0.  8 waves (2M x 4N), per-wave 128x64, BK=64, LDS 128KB.
// Per K-tile t (buf db=t&1), ONE barrier per region:
//  region A: read A(16)+bL(4); stage B(t+1)->db^1; lgkm0; 32 MFMA (n0-1); bar
//  region B: read bH(4); stage A(t+2)->db; lgkm0; 32 MFMA (n2-3); vmcnt(4); bar
// OUT_MODE: 1 = bf16 row-major; 2 = f32 scatter through window-reverse to
// out[b,c,64,64,64] (fuses the reverse kernel into the epilogue).
template <int OUT_MODE>
__global__ __launch_bounds__(512, 2) void gemm256(
    const unsigned short* __restrict__ A,   // M x K bf16
    const unsigned short* __restrict__ W,   // Nout x K bf16
    const float* __restrict__ bias,         // Nout f32
    void* __restrict__ Cv,                  // out per OUT_MODE
    int M, int Nout, int K)
{
    __shared__ unsigned short ldsA[2][2][128 * 64];
    __shared__ unsigned short ldsB[2][2][128 * 64];

    const int tid  = threadIdx.x;
    const int wave = tid >> 6;
    const int lane = tid & 63;

    // L2-locality mapping (bijective, gm=64): XCD x owns m-band x; 8m x 4n
    // macro-tiles of 32 blocks = the concurrent set per XCD.
    const int f   = blockIdx.x;
    const int xcd = f & 7;
    const int r_  = f >> 3;
    const int mac = r_ >> 5;
    const int w_  = r_ & 31;
    const int bm  = (xcd * 8 + (w_ & 7)) * 256;
    const int bn  = (mac * 4 + (w_ >> 3)) * 256;

    const int wi    = wave >> 2;        // 0/1: M half
    const int wj    = wave & 3;         // 0-3: N quarter
    const int bhalf = wj >> 1;          // B half this wave reads
    const int bcol  = (wj & 1) * 64;    // col base within that half

    const int lrow = lane & 15;
    const int kq   = lane >> 4;                    // 0-3
    const int s0   = ((kq ^ (lrow & 7)) << 3);     // swizzled elem offset

    f32x4 acc[8][4] = {};

    const int nkt = K >> 6;

    const int srl   = lane >> 3;                         // 0-7
    const int sslot = (((lane & 7) ^ srl) << 3);         // pre-swizzled src off

    auto stA = [&](int db, int half, int tt) {
        const unsigned short* gb = A + (size_t)(bm + half * 128) * K + tt * 64;
        unsigned short* lb = &ldsA[db][half][0];
        #pragma unroll
        for (int q = 0; q < 2; ++q) {
            const int r0 = wave * 16 + q * 8;
            const unsigned short* ga = gb + (size_t)(r0 + srl) * K + sslot;
            __builtin_amdgcn_global_load_lds(
                (const __attribute__((address_space(1))) void*)ga,
                (__attribute__((address_space(3))) void*)(lb + r0 * 64),
                16, 0, 0);
        }
    };
    auto stB = [&](int db, int half, int tt) {
        const unsigned short* gb = W + (size_t)(bn + half * 128) * K + tt * 64;
        unsigned short* lb = &ldsB[db][half][0];
        #pragma unroll
        for (int q = 0; q < 2; ++q) {
            const int r0 = wave * 16 + q * 8;
            const unsigned short* ga = gb + (size_t)(r0 + srl) * K + sslot;
            __builtin_amdgcn_global_load_lds(
                (const __attribute__((address_space(1))) void*)ga,
                (__attribute__((address_space(3))) void*)(lb + r0 * 64),
                16, 0, 0);
        }
    };

    // ---- prologue: A(0), B(0); A(1) rides
    stA(0, 0, 0); stA(0, 1, 0);
    stB(0, 0, 0); stB(0, 1, 0);
    stA(1, 0, 1); stA(1, 1, 1);
    VMCNT(4);
    BARRIER();

    for (int t = 0; t < nkt; ++t) {
        const int db = t & 1;
        const unsigned short* hA = &ldsA[db][wi][0];
        const unsigned short* hB = &ldsB[db][bhalf][0];

        s16x8 a[8][2], bl[2][2], bh[2][2];

        // ===== region A: n-quadrants 0-1; stage B(t+1) -> db^1
        #pragma unroll
        for (int m = 0; m < 8; ++m) {
            const int rb = (m * 16 + lrow) * 64;
            a[m][0] = *(const s16x8*)&hA[rb + s0];
            a[m][1] = *(const s16x8*)&hA[rb + (s0 ^ 32)];
        }
        #pragma unroll
        for (int n = 0; n < 2; ++n) {
            const int rb = (bcol + n * 16 + lrow) * 64;
            bl[n][0] = *(const s16x8*)&hB[rb + s0];
            bl[n][1] = *(const s16x8*)&hB[rb + (s0 ^ 32)];
        }
        if (t + 1 < nkt) { stB(db ^ 1, 0, t + 1); stB(db ^ 1, 1, t + 1); }
        LGKM0();
        __builtin_amdgcn_s_setprio(1);
        #pragma unroll
        for (int m = 0; m < 8; ++m)
            #pragma unroll
            for (int n = 0; n < 2; ++n) {
                acc[m][n] = __builtin_amdgcn_mfma_f32_16x16x32_bf16(a[m][0], bl[n][0], acc[m][n], 0, 0, 0);
                acc[m][n] = __builtin_amdgcn_mfma_f32_16x16x32_bf16(a[m][1], bl[n][1], acc[m][n], 0, 0, 0);
            }
        __builtin_amdgcn_s_setprio(0);
        BARRIER();

        // ===== region B: n-quadrants 2-3; stage A(t+2) -> db
        #pragma unroll
        for (int n = 0; n < 2; ++n) {
            const int rb = (bcol + (n + 2) * 16 + lrow) * 64;
            bh[n][0] = *(const s16x8*)&hB[rb + s0];
            bh[n][1] = *(const s16x8*)&hB[rb + (s0 ^ 32)];
        }
        if (t + 2 < nkt) { stA(db, 0, t + 2); stA(db, 1, t + 2); }
        LGKM0();
        __builtin_amdgcn_s_setprio(1);
        #pragma unroll
        for (int m = 0; m < 8; ++m)
            #pragma unroll
            for (int n = 0; n < 2; ++n) {
                acc[m][n + 2] = __builtin_amdgcn_mfma_f32_16x16x32_bf16(a[m][0], bh[n][0], acc[m][n + 2], 0, 0, 0);
                acc[m][n + 2] = __builtin_amdgcn_mfma_f32_16x16x32_bf16(a[m][1], bh[n][1], acc[m][n + 2], 0, 0, 0);
            }
        __builtin_amdgcn_s_setprio(0);
        if (t + 2 < nkt)      { VMCNT(4); }   // tile t+1 fully resident
        else                  { VMCNT(0); }   // drain tail
        BARRIER();
    }

    // ---- epilogue: C/D layout col=lane&15, row=(lane>>4)*4+reg
    const int rowbase = bm + wi * 128 + (kq << 2);
    const int colbase = bn + wj * 64 + lrow;
    float bv[4];
    #pragma unroll
    for (int n = 0; n < 4; ++n) bv[n] = bias[colbase + n * 16];

    if (OUT_MODE == 1) {
        unsigned short* C = (unsigned short*)Cv;
        #pragma unroll
        for (int m = 0; m < 8; ++m) {
            #pragma unroll
            for (int r = 0; r < 4; ++r) {
                const int rr = rowbase + m * 16 + r;
                #pragma unroll
                for (int n = 0; n < 4; ++n) {
                    const int cc = colbase + n * 16;
                    C[(size_t)rr * Nout + cc] = f2bf(acc[m][n][r] + bv[n]);
                }
            }
        }
    } else {
        // window-reverse scatter: rr=(b,nx,ny,nz), cc=(c,px,py,pz) ->
        // out[b,c, px*16+nx, py*16+ny, pz*16+nz]; r = nz-consecutive -> f32x4
        float* outp = (float*)Cv;
        #pragma unroll
        for (int n = 0; n < 4; ++n) {
            const int cc = colbase + n * 16;
            const int c  = cc >> 6, px = (cc >> 4) & 3,
                      py = (cc >> 2) & 3, pz = cc & 3;
            #pragma unroll
            for (int m = 0; m < 8; ++m) {
                const int rr0 = rowbase + m * 16;
                const int b   = rr0 >> 12, nx = (rr0 >> 8) & 15,
                          ny  = (rr0 >> 4) & 15, nz0 = rr0 & 15;
                float* dst = outp
                    + ((size_t)((b * NC + c) * 64 + px * 16 + nx)) * 4096
                    + (size_t)(py * 16 + ny) * 64 + pz * 16 + nz0;
                f32x4 w = {acc[m][n][0] + bv[n], acc[m][n][1] + bv[n],
                           acc[m][n][2] + bv[n], acc[m][n][3] + bv[n]};
                *(f32x4*)dst = w;
            }
        }
    }
}

// ---------------- attention over B axis: seq=4, batch = N*H ----------------
// block = token n (4096 blocks, 512 thr); wave handles 2 heads; u16x4 loads.
__global__ __launch_bounds__(512) void attn_kernel(
    const unsigned short* __restrict__ qkv, unsigned short* __restrict__ o)
{
    const int n    = blockIdx.x;
    const int wave = threadIdx.x >> 6;
    const int lane = threadIdx.x & 63;
    const int h    = wave * 2 + (lane >> 5);
    const int dl   = (lane & 31) * 4;
    const float scale = 0.0883883476483184405501f;  // 1/sqrt(128)

    float q[4][4], k[4][4], v[4][4];
    #pragma unroll
    for (int b = 0; b < 4; ++b) {
        size_t base = (size_t)(b * NTOK + n) * (3 * ED) + h * HD + dl;
        u16x4 uq = *(const u16x4*)&qkv[base];
        u16x4 uk = *(const u16x4*)&qkv[base + ED];
        u16x4 uv = *(const u16x4*)&qkv[base + 2 * ED];
        #pragma unroll
        for (int i = 0; i < 4; ++i) {
            q[b][i] = bf2f(uq[i]); k[b][i] = bf2f(uk[i]); v[b][i] = bf2f(uv[i]);
        }
    }

    float sc[4][4];
    #pragma unroll
    for (int s = 0; s < 4; ++s) {
        #pragma unroll
        for (int t = 0; t < 4; ++t) {
            float p = q[s][0] * k[t][0] + q[s][1] * k[t][1]
                    + q[s][2] * k[t][2] + q[s][3] * k[t][3];
            #pragma unroll
            for (int off = 16; off > 0; off >>= 1)   // reduce within 32-group
                p += __shfl_xor(p, off, 64);
            sc[s][t] = p * scale;
        }
    }

    #pragma unroll
    for (int s = 0; s < 4; ++s) {
        float mx = fmaxf(fmaxf(sc[s][0], sc[s][1]), fmaxf(sc[s][2], sc[s][3]));
        float e0 = __expf(sc[s][0] - mx);
        float e1 = __expf(sc[s][1] - mx);
        float e2 = __expf(sc[s][2] - mx);
        float e3 = __expf(sc[s][3] - mx);
        float inv = 1.0f / (e0 + e1 + e2 + e3);
        u16x4 ov;
        #pragma unroll
        for (int i = 0; i < 4; ++i) {
            float oo = (e0 * v[0][i] + e1 * v[1][i] + e2 * v[2][i] + e3 * v[3][i]) * inv;
            ov[i] = f2bf(oo);
        }
        *(u16x4*)&o[(size_t)(s * NTOK + n) * ED + h * HD + dl] = ov;
    }
}

// ---------------------------------------------------------------------------
extern "C" void kernel_launch(void* const* d_in, const int* in_sizes, int n_in,
                              void* d_out, int out_size, void* d_ws, size_t ws_size,
                              hipStream_t stream) {
    const float* x          = (const float*)d_in[0];
    const float* in_proj_w  = (const float*)d_in[1];
    const float* in_proj_b  = (const float*)d_in[2];
    const float* out_proj_w = (const float*)d_in[3];
    const float* out_proj_b = (const float*)d_in[4];
    const float* mlp_w      = (const float*)d_in[5];
    const float* mlp_b      = (const float*)d_in[6];
    float* out = (float*)d_out;

    const size_t M = 16384;                       // B*N rows
    char* ws = (char*)d_ws;
    size_t off = 0;
    unsigned short* tok    = (unsigned short*)(ws + off); off += M * ED * 2;
    unsigned short* w_in   = (unsigned short*)(ws + off); off += (size_t)3 * ED * ED * 2;
    unsigned short* w_mlp  = (unsigned short*)(ws + off); off += (size_t)ED * ED * 2;
    unsigned short* w_outT = (unsigned short*)(ws + off); off += (size_t)ED * ED * 2;
    unsigned short* w_comb = (unsigned short*)(ws + off); off += (size_t)ED * ED * 2;
    float* zbias           = (float*)(ws + off);          off += ED * 4;
    float* b_comb          = (float*)(ws + off);          off += ED * 4;
    unsigned short* obuf   = (unsigned short*)(ws + off); off += M * ED * 2;
    unsigned short* qkv    = (unsigned short*)(ws + off); off += M * 3 * ED * 2;

    if (ws_size < off) {
        fprintf(stderr, "kernel_launch: ws too small (%zu < %zu)\n", ws_size, off);
        return;
    }

    // weight converts + transpose
    {
        int n4 = 3 * ED * ED / 4;
        f32_to_bf16_kernel<<<(n4 + 255) / 256, 256, 0, stream>>>(in_proj_w, w_in, n4);
        n4 = ED * ED / 4;
        f32_to_bf16_kernel<<<(n4 + 255) / 256, 256, 0, stream>>>(mlp_w, w_mlp, n4);
        transpose_bf16_kernel<<<dim3(ED / 64, ED / 64), 256, 0, stream>>>(
            out_proj_w, w_outT, ED);
        hipMemsetAsync(zbias, 0, ED * sizeof(float), stream);
    }

    // W_comb = mlp_w @ out_proj_w  (row-major [j][k]); 2048^3, 128^2-tile MFMA
    gemm128<<<dim3(ED / 128, ED / 128), 256, 0, stream>>>(
        w_mlp, w_outT, zbias, w_comb, ED, ED, ED);
    // b_comb = mlp_w @ out_proj_b + mlp_b
    bcomb_kernel<<<ED / 4, 256, 0, stream>>>(mlp_w, out_proj_b, mlp_b, b_comb);

    // window partition
    partition_kernel<<<(NB * NC * 64 * 64 * 16) / 256, 256, 0, stream>>>(x, tok);

    // qkv = tok @ in_proj_w^T + in_proj_b   (16384 x 6144 x 2048)
    gemm256<1><<<dim3(64 * (6144 / 256)), 512, 0, stream>>>(
        tok, w_in, in_proj_b, qkv, 16384, 6144, 2048);

    // attention (seq=B=4, batch=N*H)
    attn_kernel<<<NTOK, 512, 0, stream>>>(qkv, obuf);

    // out = reverse(obuf @ W_comb^T + b_comb)  -- scatter epilogue
    gemm256<2><<<dim3(64 * (2048 / 256)), 512, 0, stream>>>(
        obuf, w_comb, b_comb, out, 16384, 2048, 2048);
}

// Round 8
// 665.331 us; speedup vs baseline: 1.4797x; 1.0020x over previous
//
#include <hip/hip_runtime.h>
#include <stdio.h>

// ---------------------------------------------------------------------------
// WindowAttention: partition -> QKV gemm -> attention over B axis ->
// fused (out_proj @ mlp) gemm with window-reverse scatter epilogue.
// GEMM: 256x256 bf16 MFMA with k-half register double-buffering:
//   frag sets {A0,B0} / {A1,B1} alternate per k-half so ds_reads of one half
//   overlap MFMAs of the other (breaks the WAR chain that serialized r4).
//   Staging/vmcnt skeleton identical to round-4 (hazard proof unchanged).
// ---------------------------------------------------------------------------

typedef __attribute__((ext_vector_type(4))) float f32x4;
typedef __attribute__((ext_vector_type(8))) short s16x8;
typedef __attribute__((ext_vector_type(2))) unsigned short u16x2;
typedef __attribute__((ext_vector_type(4))) unsigned short u16x4;

#define NB 4        // batch B (attention seq len)
#define NC 32       // channels
#define NTOK 4096   // N = 16^3 windows
#define ED 2048     // embed dim E
#define NH 16       // heads
#define HD 128      // head dim

__device__ __forceinline__ unsigned short f2bf(float f) {
    union { float f; unsigned int u; } v; v.f = f;
    unsigned int r = (v.u + 0x7fffu + ((v.u >> 16) & 1u)) >> 16;
    return (unsigned short)r;
}
__device__ __forceinline__ float bf2f(unsigned short u) {
    union { unsigned int u; float f; } v; v.u = ((unsigned int)u) << 16;
    return v.f;
}

#define BARRIER() asm volatile("s_barrier" ::: "memory")
#define LGKM0() do { asm volatile("s_waitcnt lgkmcnt(0)" ::: "memory"); \
                     __builtin_amdgcn_sched_barrier(0); } while (0)
#define LGKM12() do { asm volatile("s_waitcnt lgkmcnt(12)" ::: "memory"); \
                      __builtin_amdgcn_sched_barrier(0); } while (0)
#define VMCNT(n) asm volatile("s_waitcnt vmcnt(" #n ")" ::: "memory")
#define SEAM() __builtin_amdgcn_sched_barrier(0)

// ---------------- fp32 -> bf16 convert (weights) ----------------
__global__ void f32_to_bf16_kernel(const float* __restrict__ src,
                                   unsigned short* __restrict__ dst, int n4) {
    int i = blockIdx.x * blockDim.x + threadIdx.x;
    if (i >= n4) return;
    f32x4 v = *(const f32x4*)(src + (size_t)i * 4);
    u16x4 w;
    w.x = f2bf(v.x); w.y = f2bf(v.y); w.z = f2bf(v.z); w.w = f2bf(v.w);
    *(u16x4*)(dst + (size_t)i * 4) = w;
}

// ---------------- transpose f32 -> bf16: dst[j,k] = src[k,j] ----------------
__global__ __launch_bounds__(256) void transpose_bf16_kernel(
    const float* __restrict__ src, unsigned short* __restrict__ dst, int n) {
    __shared__ float lds[64][68];
    const int bx = blockIdx.x * 64;   // j base
    const int by = blockIdx.y * 64;   // k base
    const int t  = threadIdx.x;
    const int r  = t >> 2;            // 0..63
    const int c4 = (t & 3) * 16;      // 0/16/32/48
    const float* s = src + (size_t)(by + r) * n + bx + c4;
    #pragma unroll
    for (int i = 0; i < 4; ++i)
        *(f32x4*)&lds[r][c4 + i * 4] = *(const f32x4*)(s + i * 4);
    __syncthreads();
    unsigned short* d = dst + (size_t)(bx + r) * n + by + c4;
    #pragma unroll
    for (int i = 0; i < 4; ++i) {
        u16x4 w;
        w.x = f2bf(lds[c4 + i * 4 + 0][r]);
        w.y = f2bf(lds[c4 + i * 4 + 1][r]);
        w.z = f2bf(lds[c4 + i * 4 + 2][r]);
        w.w = f2bf(lds[c4 + i * 4 + 3][r]);
        *(u16x4*)(d + i * 4) = w;
    }
}

// ---------------- b_comb = mlp_w @ out_proj_b + mlp_b (wave per row) -------
__global__ __launch_bounds__(256) void bcomb_kernel(
    const float* __restrict__ mlp_w, const float* __restrict__ opb,
    const float* __restrict__ mlpb, float* __restrict__ bcomb) {
    const int wave = threadIdx.x >> 6, lane = threadIdx.x & 63;
    const int row = blockIdx.x * 4 + wave;
    const float* r = mlp_w + (size_t)row * ED;
    float s = 0.0f;
    for (int k = lane * 4; k < ED; k += 256) {
        f32x4 a = *(const f32x4*)(r + k);
        f32x4 b = *(const f32x4*)(opb + k);
        s += a.x * b.x + a.y * b.y + a.z * b.z + a.w * b.w;
    }
    #pragma unroll
    for (int off = 32; off > 0; off >>= 1) s += __shfl_xor(s, off, 64);
    if (lane == 0) bcomb[row] = s + mlpb[row];
}

// ---------------- window partition: x -> tok (B,N,E) bf16 ----------------
__global__ void partition_kernel(const float* __restrict__ x,
                                 unsigned short* __restrict__ tok) {
    int idx = blockIdx.x * blockDim.x + threadIdx.x;
    int m = idx & 15;
    int t = idx >> 4;
    int Y = t & 63; t >>= 6;
    int X = t & 63; t >>= 6;
    int c = t & 31;
    int b = t >> 5;
    f32x4 xv = *(const f32x4*)(x + (size_t)idx * 4);
    int nx = X >> 2, px = X & 3;
    int ny = Y >> 2, py = Y & 3;
    int n = nx * 256 + ny * 16 + m;
    int e = c * 64 + px * 16 + py * 4;
    size_t dst = (size_t)(b * NTOK + n) * ED + e;
    u16x4 w;
    w.x = f2bf(xv.x); w.y = f2bf(xv.y); w.z = f2bf(xv.z); w.w = f2bf(xv.w);
    *(u16x4*)&tok[dst] = w;
}

// ---------------- 128x128 4-wave bf16 GEMM (for small W_comb job) ----------
__global__ __launch_bounds__(256) void gemm128(
    const unsigned short* __restrict__ A,   // M x K bf16
    const unsigned short* __restrict__ W,   // Nout x K bf16
    const float* __restrict__ bias,         // Nout f32
    unsigned short* __restrict__ C,         // M x Nout bf16
    int M, int Nout, int K)
{
    __shared__ unsigned short ldsA[128 * 64];
    __shared__ unsigned short ldsW[128 * 64];

    const int tid  = threadIdx.x;
    const int wave = tid >> 6;
    const int lane = tid & 63;
    const int bm = blockIdx.x * 128;
    const int bn = blockIdx.y * 128;
    const int wm = (wave >> 1) * 64;
    const int wn = (wave & 1) * 64;

    f32x4 acc[4][4] = {};

    const int srow = lane >> 3;
    const int scol = (lane & 7) * 8;
    const int lrow = lane & 15;
    const int lk   = (lane >> 4) * 8;

    const int nkt = K >> 6;
    for (int kt = 0; kt < nkt; ++kt) {
        const int kbase = kt * 64;
        #pragma unroll
        for (int q = 0; q < 4; ++q) {
            int chunk = wave * 4 + q;
            int row = chunk * 8 + srow;
            const unsigned short* ga = A + (size_t)(bm + row) * K + kbase + scol;
            const unsigned short* gw = W + (size_t)(bn + row) * K + kbase + scol;
            __builtin_amdgcn_global_load_lds(
                (const __attribute__((address_space(1))) void*)ga,
                (__attribute__((address_space(3))) void*)(&ldsA[chunk * 512]),
                16, 0, 0);
            __builtin_amdgcn_global_load_lds(
                (const __attribute__((address_space(1))) void*)gw,
                (__attribute__((address_space(3))) void*)(&ldsW[chunk * 512]),
                16, 0, 0);
        }
        __syncthreads();

        #pragma unroll
        for (int ks = 0; ks < 2; ++ks) {
            const int k0 = ks * 32 + lk;
            s16x8 af[4], bf[4];
            #pragma unroll
            for (int m = 0; m < 4; ++m)
                af[m] = *(const s16x8*)&ldsA[(wm + m * 16 + lrow) * 64 + k0];
            #pragma unroll
            for (int n = 0; n < 4; ++n)
                bf[n] = *(const s16x8*)&ldsW[(wn + n * 16 + lrow) * 64 + k0];
            #pragma unroll
            for (int m = 0; m < 4; ++m)
                #pragma unroll
                for (int n = 0; n < 4; ++n)
                    acc[m][n] = __builtin_amdgcn_mfma_f32_16x16x32_bf16(
                        af[m], bf[n], acc[m][n], 0, 0, 0);
        }
        __syncthreads();
    }

    const int col   = lane & 15;
    const int rbase = (lane >> 4) * 4;
    #pragma unroll
    for (int n = 0; n < 4; ++n) {
        int cc = bn + wn + n * 16 + col;
        float bv = bias[cc];
        #pragma unroll
        for (int m = 0; m < 4; ++m)
            #pragma unroll
            for (int r = 0; r < 4; ++r) {
                int rr = bm + wm + m * 16 + rbase + r;
                C[(size_t)rr * Nout + cc] = f2bf(acc[m][n][r] + bv);
            }
    }
}

// ---------------- 256x256 k-half-pipelined bf16 GEMM ----------------
// C[r,j] = sum_k A[r,k] * W[j,k] + bias[j].  M == 16384, Nout % 1024 == 0.
// 8 waves (2M x 4N), per-wave 128x64, BK=64, LDS 128KB double-buffered.
// Frag sets: {A0,B0} = k-half 0, {A1,B1} = k-half 1 (96 VGPR total, same as
// the single-set layout -> no occupancy change). Per tile t (db=t&1):
//  s1 issue kh1 reads -> set1 ; stage B(t+1)->db^1
//  s3 lgkmcnt(12) [set0 drained, set1 may ride] ; MFMA kh0 (32)
//  s4 lgkm0 ; BARRIER#1 [all tile-t reads complete] ; stage A(t+2)->db
//  s6 MFMA kh1 (32)
//  s7 vmcnt(4) [A(t+1),B(t+1) landed; A(t+2) rides] ; BARRIER#2
//  s8 issue kh0(t+1) reads -> set0 [tile t+1 resident]
// The WAR chain is broken: reads of one set overlap MFMAs of the other.
// OUT_MODE: 1 = bf16 row-major; 2 = f32 window-reverse scatter.
template <int OUT_MODE>
__global__ __launch_bounds__(512, 2) void gemm256(
    const unsigned short* __restrict__ A,   // M x K bf16
    const unsigned short* __restrict__ W,   // Nout x K bf16
    const float* __restrict__ bias,         // Nout f32
    void* __restrict__ Cv,                  // out per OUT_MODE
    int M, int Nout, int K)
{
    __shared__ unsigned short ldsA[2][2][128 * 64];
    __shared__ unsigned short ldsB[2][2][128 * 64];

    const int tid  = threadIdx.x;
    const int wave = tid >> 6;
    const int lane = tid & 63;

    // L2-locality mapping (bijective, gm=64): XCD x owns m-band x; 8m x 4n
    // macro-tiles of 32 blocks = the concurrent set per XCD.
    const int f   = blockIdx.x;
    const int xcd = f & 7;
    const int r_  = f >> 3;
    const int mac = r_ >> 5;
    const int w_  = r_ & 31;
    const int bm  = (xcd * 8 + (w_ & 7)) * 256;
    const int bn  = (mac * 4 + (w_ >> 3)) * 256;

    const int wi    = wave >> 2;        // 0/1: M half
    const int wj    = wave & 3;         // 0-3: N quarter
    const int bhalf = wj >> 1;          // B half this wave reads
    const int bcol  = (wj & 1) * 64;    // col base within that half

    const int lrow = lane & 15;
    const int kq   = lane >> 4;                    // 0-3
    const int s0   = ((kq ^ (lrow & 7)) << 3);     // swizzled elem offset (kh0)
    const int s1   = s0 ^ 32;                      // kh1

    f32x4 acc[8][4] = {};

    const int nkt = K >> 6;

    const int srl   = lane >> 3;                         // 0-7
    const int sslot = (((lane & 7) ^ srl) << 3);         // pre-swizzled src off

    auto stA = [&](int db, int half, int tt) {
        const unsigned short* gb = A + (size_t)(bm + half * 128) * K + tt * 64;
        unsigned short* lb = &ldsA[db][half][0];
        #pragma unroll
        for (int q = 0; q < 2; ++q) {
            const int r0 = wave * 16 + q * 8;
            const unsigned short* ga = gb + (size_t)(r0 + srl) * K + sslot;
            __builtin_amdgcn_global_load_lds(
                (const __attribute__((address_space(1))) void*)ga,
                (__attribute__((address_space(3))) void*)(lb + r0 * 64),
                16, 0, 0);
        }
    };
    auto stB = [&](int db, int half, int tt) {
        const unsigned short* gb = W + (size_t)(bn + half * 128) * K + tt * 64;
        unsigned short* lb = &ldsB[db][half][0];
        #pragma unroll
        for (int q = 0; q < 2; ++q) {
            const int r0 = wave * 16 + q * 8;
            const unsigned short* ga = gb + (size_t)(r0 + srl) * K + sslot;
            __builtin_amdgcn_global_load_lds(
                (const __attribute__((address_space(1))) void*)ga,
                (__attribute__((address_space(3))) void*)(lb + r0 * 64),
                16, 0, 0);
        }
    };

    s16x8 A0[8], B0[4], A1[8], B1[4];

    // ---- prologue: A(0), B(0) -> buf0; A(1) rides
    stA(0, 0, 0); stA(0, 1, 0);
    stB(0, 0, 0); stB(0, 1, 0);
    stA(1, 0, 1); stA(1, 1, 1);
    VMCNT(4);
    BARRIER();
    {   // issue kh0(0) reads -> set0
        const unsigned short* hA = &ldsA[0][wi][0];
        const unsigned short* hB = &ldsB[0][bhalf][0];
        #pragma unroll
        for (int m = 0; m < 8; ++m)
            A0[m] = *(const s16x8*)&hA[(m * 16 + lrow) * 64 + s0];
        #pragma unroll
        for (int n = 0; n < 2; ++n) {
            B0[n]     = *(const s16x8*)&hB[(bcol + n * 16 + lrow) * 64 + s0];
            B0[n + 2] = *(const s16x8*)&hB[(bcol + (n + 2) * 16 + lrow) * 64 + s0];
        }
    }
    SEAM();

    for (int t = 0; t < nkt; ++t) {
        const int db = t & 1;
        const unsigned short* hA = &ldsA[db][wi][0];
        const unsigned short* hB = &ldsB[db][bhalf][0];

        // ===== s1: issue kh1(t) reads -> set1
        #pragma unroll
        for (int m = 0; m < 8; ++m)
            A1[m] = *(const s16x8*)&hA[(m * 16 + lrow) * 64 + s1];
        #pragma unroll
        for (int n = 0; n < 2; ++n) {
            B1[n]     = *(const s16x8*)&hB[(bcol + n * 16 + lrow) * 64 + s1];
            B1[n + 2] = *(const s16x8*)&hB[(bcol + (n + 2) * 16 + lrow) * 64 + s1];
        }
        SEAM();

        // ===== s2: stage B(t+1) -> db^1
        if (t + 1 < nkt) { stB(db ^ 1, 0, t + 1); stB(db ^ 1, 1, t + 1); }

        // ===== s3: set0 resident (oldest 12); MFMA kh0
        LGKM12();
        __builtin_amdgcn_s_setprio(1);
        #pragma unroll
        for (int m = 0; m < 8; ++m)
            #pragma unroll
            for (int n = 0; n < 2; ++n) {
                acc[m][n]     = __builtin_amdgcn_mfma_f32_16x16x32_bf16(A0[m], B0[n],     acc[m][n],     0, 0, 0);
                acc[m][n + 2] = __builtin_amdgcn_mfma_f32_16x16x32_bf16(A0[m], B0[n + 2], acc[m][n + 2], 0, 0, 0);
            }
        __builtin_amdgcn_s_setprio(0);
        SEAM();

        // ===== s4: all tile-t reads drained; barrier; stage A(t+2) -> db
        LGKM0();
        BARRIER();     // #1
        if (t + 2 < nkt) { stA(db, 0, t + 2); stA(db, 1, t + 2); }

        // ===== s6: MFMA kh1
        __builtin_amdgcn_s_setprio(1);
        #pragma unroll
        for (int m = 0; m < 8; ++m)
            #pragma unroll
            for (int n = 0; n < 2; ++n) {
                acc[m][n]     = __builtin_amdgcn_mfma_f32_16x16x32_bf16(A1[m], B1[n],     acc[m][n],     0, 0, 0);
                acc[m][n + 2] = __builtin_amdgcn_mfma_f32_16x16x32_bf16(A1[m], B1[n + 2], acc[m][n + 2], 0, 0, 0);
            }
        __builtin_amdgcn_s_setprio(0);
        SEAM();

        // ===== s7: tile t+1 resident; A(t+2) rides
        if (t + 2 < nkt)      { VMCNT(4); }
        else                  { VMCNT(0); }
        BARRIER();     // #2

        // ===== s8: issue kh0(t+1) reads -> set0
        if (t + 1 < nkt) {
            const unsigned short* hA2 = &ldsA[db ^ 1][wi][0];
            const unsigned short* hB2 = &ldsB[db ^ 1][bhalf][0];
            #pragma unroll
            for (int m = 0; m < 8; ++m)
                A0[m] = *(const s16x8*)&hA2[(m * 16 + lrow) * 64 + s0];
            #pragma unroll
            for (int n = 0; n < 2; ++n) {
                B0[n]     = *(const s16x8*)&hB2[(bcol + n * 16 + lrow) * 64 + s0];
                B0[n + 2] = *(const s16x8*)&hB2[(bcol + (n + 2) * 16 + lrow) * 64 + s0];
            }
        }
        SEAM();
    }

    // ---- epilogue: C/D layout col=lane&15, row=(lane>>4)*4+reg
    const int rowbase = bm + wi * 128 + (kq << 2);
    const int colbase = bn + wj * 64 + lrow;
    float bv[4];
    #pragma unroll
    for (int n = 0; n < 4; ++n) bv[n] = bias[colbase + n * 16];

    if (OUT_MODE == 1) {
        unsigned short* C = (unsigned short*)Cv;
        #pragma unroll
        for (int m = 0; m < 8; ++m) {
            #pragma unroll
            for (int r = 0; r < 4; ++r) {
                const int rr = rowbase + m * 16 + r;
                #pragma unroll
                for (int n = 0; n < 4; ++n) {
                    const int cc = colbase + n * 16;
                    C[(size_t)rr * Nout + cc] = f2bf(acc[m][n][r] + bv[n]);
                }
            }
        }
    } else {
        // window-reverse scatter: rr=(b,nx,ny,nz), cc=(c,px,py,pz) ->
        // out[b,c, px*16+nx, py*16+ny, pz*16+nz]; r = nz-consecutive -> f32x4
        float* outp = (float*)Cv;
        #pragma unroll
        for (int n = 0; n < 4; ++n) {
            const int cc = colbase + n * 16;
            const int c  = cc >> 6, px = (cc >> 4) & 3,
                      py = (cc >> 2) & 3, pz = cc & 3;
            #pragma unroll
            for (int m = 0; m < 8; ++m) {
                const int rr0 = rowbase + m * 16;
                const int b   = rr0 >> 12, nx = (rr0 >> 8) & 15,
                          ny  = (rr0 >> 4) & 15, nz0 = rr0 & 15;
                float* dst = outp
                    + ((size_t)((b * NC + c) * 64 + px * 16 + nx)) * 4096
                    + (size_t)(py * 16 + ny) * 64 + pz * 16 + nz0;
                f32x4 w = {acc[m][n][0] + bv[n], acc[m][n][1] + bv[n],
                           acc[m][n][2] + bv[n], acc[m][n][3] + bv[n]};
                *(f32x4*)dst = w;
            }
        }
    }
}

// ---------------- attention over B axis: seq=4, batch = N*H ----------------
// block = token n (4096 blocks, 512 thr); wave handles 2 heads; u16x4 loads.
__global__ __launch_bounds__(512) void attn_kernel(
    const unsigned short* __restrict__ qkv, unsigned short* __restrict__ o)
{
    const int n    = blockIdx.x;
    const int wave = threadIdx.x >> 6;
    const int lane = threadIdx.x & 63;
    const int h    = wave * 2 + (lane >> 5);
    const int dl   = (lane & 31) * 4;
    const float scale = 0.0883883476483184405501f;  // 1/sqrt(128)

    float q[4][4], k[4][4], v[4][4];
    #pragma unroll
    for (int b = 0; b < 4; ++b) {
        size_t base = (size_t)(b * NTOK + n) * (3 * ED) + h * HD + dl;
        u16x4 uq = *(const u16x4*)&qkv[base];
        u16x4 uk = *(const u16x4*)&qkv[base + ED];
        u16x4 uv = *(const u16x4*)&qkv[base + 2 * ED];
        #pragma unroll
        for (int i = 0; i < 4; ++i) {
            q[b][i] = bf2f(uq[i]); k[b][i] = bf2f(uk[i]); v[b][i] = bf2f(uv[i]);
        }
    }

    float sc[4][4];
    #pragma unroll
    for (int s = 0; s < 4; ++s) {
        #pragma unroll
        for (int t = 0; t < 4; ++t) {
            float p = q[s][0] * k[t][0] + q[s][1] * k[t][1]
                    + q[s][2] * k[t][2] + q[s][3] * k[t][3];
            #pragma unroll
            for (int off = 16; off > 0; off >>= 1)   // reduce within 32-group
                p += __shfl_xor(p, off, 64);
            sc[s][t] = p * scale;
        }
    }

    #pragma unroll
    for (int s = 0; s < 4; ++s) {
        float mx = fmaxf(fmaxf(sc[s][0], sc[s][1]), fmaxf(sc[s][2], sc[s][3]));
        float e0 = __expf(sc[s][0] - mx);
        float e1 = __expf(sc[s][1] - mx);
        float e2 = __expf(sc[s][2] - mx);
        float e3 = __expf(sc[s][3] - mx);
        float inv = 1.0f / (e0 + e1 + e2 + e3);
        u16x4 ov;
        #pragma unroll
        for (int i = 0; i < 4; ++i) {
            float oo = (e0 * v[0][i] + e1 * v[1][i] + e2 * v[2][i] + e3 * v[3][i]) * inv;
            ov[i] = f2bf(oo);
        }
        *(u16x4*)&o[(size_t)(s * NTOK + n) * ED + h * HD + dl] = ov;
    }
}

// ---------------------------------------------------------------------------
extern "C" void kernel_launch(void* const* d_in, const int* in_sizes, int n_in,
                              void* d_out, int out_size, void* d_ws, size_t ws_size,
                              hipStream_t stream) {
    const float* x          = (const float*)d_in[0];
    const float* in_proj_w  = (const float*)d_in[1];
    const float* in_proj_b  = (const float*)d_in[2];
    const float* out_proj_w = (const float*)d_in[3];
    const float* out_proj_b = (const float*)d_in[4];
    const float* mlp_w      = (const float*)d_in[5];
    const float* mlp_b      = (const float*)d_in[6];
    float* out = (float*)d_out;

    const size_t M = 16384;                       // B*N rows
    char* ws = (char*)d_ws;
    size_t off = 0;
    unsigned short* tok    = (unsigned short*)(ws + off); off += M * ED * 2;
    unsigned short* w_in   = (unsigned short*)(ws + off); off += (size_t)3 * ED * ED * 2;
    unsigned short* w_mlp  = (unsigned short*)(ws + off); off += (size_t)ED * ED * 2;
    unsigned short* w_outT = (unsigned short*)(ws + off); off += (size_t)ED * ED * 2;
    unsigned short* w_comb = (unsigned short*)(ws + off); off += (size_t)ED * ED * 2;
    float* zbias           = (float*)(ws + off);          off += ED * 4;
    float* b_comb          = (float*)(ws + off);          off += ED * 4;
    unsigned short* obuf   = (unsigned short*)(ws + off); off += M * ED * 2;
    unsigned short* qkv    = (unsigned short*)(ws + off); off += M * 3 * ED * 2;

    if (ws_size < off) {
        fprintf(stderr, "kernel_launch: ws too small (%zu < %zu)\n", ws_size, off);
        return;
    }

    // weight converts + transpose
    {
        int n4 = 3 * ED * ED / 4;
        f32_to_bf16_kernel<<<(n4 + 255) / 256, 256, 0, stream>>>(in_proj_w, w_in, n4);
        n4 = ED * ED / 4;
        f32_to_bf16_kernel<<<(n4 + 255) / 256, 256, 0, stream>>>(mlp_w, w_mlp, n4);
        transpose_bf16_kernel<<<dim3(ED / 64, ED / 64), 256, 0, stream>>>(
            out_proj_w, w_outT, ED);
        hipMemsetAsync(zbias, 0, ED * sizeof(float), stream);
    }

    // W_comb = mlp_w @ out_proj_w  (row-major [j][k]); 2048^3, 128^2-tile MFMA
    gemm128<<<dim3(ED / 128, ED / 128), 256, 0, stream>>>(
        w_mlp, w_outT, zbias, w_comb, ED, ED, ED);
    // b_comb = mlp_w @ out_proj_b + mlp_b
    bcomb_kernel<<<ED / 4, 256, 0, stream>>>(mlp_w, out_proj_b, mlp_b, b_comb);

    // window partition
    partition_kernel<<<(NB * NC * 64 * 64 * 16) / 256, 256, 0, stream>>>(x, tok);

    // qkv = tok @ in_proj_w^T + in_proj_b   (16384 x 6144 x 2048)
    gemm256<1><<<dim3(64 * (6144 / 256)), 512, 0, stream>>>(
        tok, w_in, in_proj_b, qkv, 16384, 6144, 2048);

    // attention (seq=B=4, batch=N*H)
    attn_kernel<<<NTOK, 512, 0, stream>>>(qkv, obuf);

    // out = reverse(obuf @ W_comb^T + b_comb)  -- scatter epilogue
    gemm256<2><<<dim3(64 * (2048 / 256)), 512, 0, stream>>>(
        obuf, w_comb, b_comb, out, 16384, 2048, 2048);
}